// Round 3
// baseline (5754.856 us; speedup 1.0000x reference)
//
#include <hip/hip_runtime.h>

// Problem constants
constexpr int Bc = 32, Tc = 64, Cc = 3, Hc = 32, Wc = 32;
constexpr int F = Bc * Tc;              // 2048 frames
constexpr int FEATN = 2 * Cc * Hc * Wc; // 6144
constexpr int HID = 200;

// ---------------------------------------------------------------------------
// Transpose [B,C,H,W,T] -> [B*T, C, H, W]   (frame f = b*T + t)
// One block per (b,c,h): loads 32(w)x64(t) tile coalesced, writes coalesced.
// ---------------------------------------------------------------------------
__global__ __launch_bounds__(256)
void transpose_kernel(const float* __restrict__ x, float* __restrict__ xt) {
    __shared__ float lds[32 * 65];
    int bid = blockIdx.x;                 // ((b*3 + c)*32 + h)
    int h = bid & 31;
    int c = (bid >> 5) % 3;
    int b = bid / (3 * 32);
    const float* src = x + (size_t)bid * 2048;   // [w][t] tile, contiguous
#pragma unroll
    for (int j = 0; j < 8; ++j) {
        int i = threadIdx.x + j * 256;           // i = w*64 + t
        lds[(i >> 6) * 65 + (i & 63)] = src[i];
    }
    __syncthreads();
#pragma unroll
    for (int j = 0; j < 8; ++j) {
        int i = threadIdx.x + j * 256;           // i = t*32 + w
        int t = i >> 5, w = i & 31;
        int f = b * 64 + t;
        xt[((size_t)(f * 3 + c) << 10) + h * 32 + w] = lds[w * 65 + t];
    }
}

// ---------------------------------------------------------------------------
// Direct 3x3 conv, SAME padding, optional dual-input (implicit concat) with
// optional nearest-2x upsample of input1. Weights staged in LDS.
// in1: [F, CIN1, H(/2 if UP1), W(/2 if UP1)]; in2: [F, CIN2, H, W]
// w: [COUT, CIN1+CIN2, 3, 3] (OIHW, cross-correlation)
// ---------------------------------------------------------------------------
template<int CIN1, int CIN2, int COUT, int H, int W, bool UP1, bool RELU>
__global__ __launch_bounds__(256)
void conv3x3_kernel(const float* __restrict__ in1, const float* __restrict__ in2,
                    const float* __restrict__ wgt, const float* __restrict__ bias,
                    float* __restrict__ out) {
    constexpr int CTOT = CIN1 + CIN2;
    constexpr int NW = COUT * CTOT * 9;
    __shared__ float wlds[NW];
    for (int i = threadIdx.x; i < NW; i += 256) wlds[i] = wgt[i];
    __syncthreads();

    int tid = blockIdx.x * 256 + threadIdx.x;
    constexpr int total = F * COUT * H * W;
    if (tid >= total) return;

    int xx0 = tid % W;
    int yy0 = (tid / W) % H;
    int co  = (tid / (W * H)) % COUT;
    int f   = tid / (W * H * COUT);

    float acc = bias[co];
    const float* wrow = &wlds[co * CTOT * 9];

    // input1 channels (possibly upsampled)
    for (int ci = 0; ci < CIN1; ++ci) {
        const float* wp = wrow + ci * 9;
        const float* ib;
        if (UP1) ib = in1 + ((size_t)(f * CIN1 + ci)) * (H / 2) * (W / 2);
        else     ib = in1 + ((size_t)(f * CIN1 + ci)) * H * W;
#pragma unroll
        for (int kh = 0; kh < 3; ++kh) {
            int yy = yy0 + kh - 1;
            if (yy < 0 || yy >= H) continue;
#pragma unroll
            for (int kw = 0; kw < 3; ++kw) {
                int xx = xx0 + kw - 1;
                if (xx < 0 || xx >= W) continue;
                float v;
                if (UP1) v = ib[(yy >> 1) * (W / 2) + (xx >> 1)];
                else     v = ib[yy * W + xx];
                acc = fmaf(v, wp[kh * 3 + kw], acc);
            }
        }
    }
    // input2 channels (skip connection, full resolution)
    if constexpr (CIN2 > 0) {
        for (int ci = 0; ci < CIN2; ++ci) {
            const float* wp = wrow + (CIN1 + ci) * 9;
            const float* ib = in2 + ((size_t)(f * CIN2 + ci)) * H * W;
#pragma unroll
            for (int kh = 0; kh < 3; ++kh) {
                int yy = yy0 + kh - 1;
                if (yy < 0 || yy >= H) continue;
#pragma unroll
                for (int kw = 0; kw < 3; ++kw) {
                    int xx = xx0 + kw - 1;
                    if (xx < 0 || xx >= W) continue;
                    acc = fmaf(ib[yy * W + xx], wp[kh * 3 + kw], acc);
                }
            }
        }
    }
    if (RELU) acc = fmaxf(acc, 0.0f);
    out[tid] = acc;
}

// ---------------------------------------------------------------------------
// 2x2 max pool, stride 2
// ---------------------------------------------------------------------------
template<int CH, int H, int W>
__global__ __launch_bounds__(256)
void pool2_kernel(const float* __restrict__ in, float* __restrict__ out) {
    int tid = blockIdx.x * 256 + threadIdx.x;
    constexpr int total = F * CH * (H / 2) * (W / 2);
    if (tid >= total) return;
    int x = tid % (W / 2);
    int y = (tid / (W / 2)) % (H / 2);
    int fc = tid / ((W / 2) * (H / 2));   // f*CH + c
    const float* ib = in + (size_t)fc * H * W + (2 * y) * W + 2 * x;
    float m = fmaxf(fmaxf(ib[0], ib[1]), fmaxf(ib[W], ib[W + 1]));
    out[tid] = m;
}

// ---------------------------------------------------------------------------
// 1x1 out-conv (8->2) + softmax over [l0, l1, 1] + mask*x -> feat [F, 6144]
// One thread per (f, h, w).
// ---------------------------------------------------------------------------
__global__ __launch_bounds__(256)
void maskfeat_kernel(const float* __restrict__ d1, const float* __restrict__ xt,
                     const float* __restrict__ ow, const float* __restrict__ ob,
                     float* __restrict__ feat) {
    int tid = blockIdx.x * 256 + threadIdx.x;
    if (tid >= F * 1024) return;
    int hw = tid & 1023;
    int f  = tid >> 10;
    const float* db = d1 + ((size_t)f << 13) + hw;   // f*8*1024
    float l0 = ob[0], l1 = ob[1];
#pragma unroll
    for (int c = 0; c < 8; ++c) {
        float v = db[c << 10];
        l0 = fmaf(v, ow[c], l0);
        l1 = fmaf(v, ow[8 + c], l1);
    }
    float mx = fmaxf(fmaxf(l0, l1), 1.0f);
    float e0 = expf(l0 - mx), e1 = expf(l1 - mx), e2 = expf(1.0f - mx);
    float inv = 1.0f / (e0 + e1 + e2);
    float m0 = e0 * inv, m1 = e1 * inv;
    const float* xb = xt + (size_t)f * 3072 + hw;
    float* fb = feat + (size_t)f * 6144 + hw;
#pragma unroll
    for (int c = 0; c < 3; ++c) {
        float xv = xb[c << 10];
        fb[c << 10]          = m0 * xv;
        fb[3072 + (c << 10)] = m1 * xv;
    }
}

// ---------------------------------------------------------------------------
// FC + ReLU:  out[F,N] = relu(A[F,K] @ W[K,N] + b)
// Block: 256 threads (cols), ROWS rows per block. A-loads are block-uniform.
// ---------------------------------------------------------------------------
template<int ROWS>
__global__ __launch_bounds__(256)
void fc_relu_kernel(const float* __restrict__ A, const float* __restrict__ Wm,
                    const float* __restrict__ bias, float* __restrict__ out,
                    int K, int N) {
    int col = threadIdx.x;
    int row0 = blockIdx.x * ROWS;
    if (col >= N) return;
    float acc[ROWS];
#pragma unroll
    for (int r = 0; r < ROWS; ++r) acc[r] = 0.0f;
    for (int k = 0; k < K; ++k) {
        float wv = Wm[k * N + col];
#pragma unroll
        for (int r = 0; r < ROWS; ++r)
            acc[r] = fmaf(A[(row0 + r) * K + k], wv, acc[r]);
    }
    float bv = bias[col];
#pragma unroll
    for (int r = 0; r < ROWS; ++r)
        out[(row0 + r) * N + col] = fmaxf(acc[r] + bv, 0.0f);
}

// ---------------------------------------------------------------------------
// FC3 (200 -> 4) + tanh epilogue: out = tanh(loc)*16 + 16
// ---------------------------------------------------------------------------
__global__ __launch_bounds__(256)
void fc3_tanh_kernel(const float* __restrict__ A, const float* __restrict__ Wm,
                     const float* __restrict__ bias, float* __restrict__ out) {
    int tid = blockIdx.x * 256 + threadIdx.x;
    if (tid >= F * 4) return;
    int j = tid & 3, row = tid >> 2;
    float acc = bias[j];
    const float* ar = A + row * 200;
    for (int k = 0; k < 200; ++k)
        acc = fmaf(ar[k], Wm[k * 4 + j], acc);
    out[tid] = tanhf(acc) * 16.0f + 16.0f;
}

// ---------------------------------------------------------------------------
extern "C" void kernel_launch(void* const* d_in, const int* in_sizes, int n_in,
                              void* d_out, int out_size, void* d_ws, size_t ws_size,
                              hipStream_t stream) {
    const float* x      = (const float*)d_in[0];
    const float* enc_w1 = (const float*)d_in[1];
    const float* enc_b1 = (const float*)d_in[2];
    const float* enc_w2 = (const float*)d_in[3];
    const float* enc_b2 = (const float*)d_in[4];
    const float* enc_w3 = (const float*)d_in[5];
    const float* enc_b3 = (const float*)d_in[6];
    const float* dec_w2 = (const float*)d_in[7];
    const float* dec_b2 = (const float*)d_in[8];
    const float* dec_w1 = (const float*)d_in[9];
    const float* dec_b1 = (const float*)d_in[10];
    const float* out_w  = (const float*)d_in[11];
    const float* out_b  = (const float*)d_in[12];
    const float* loc_w1 = (const float*)d_in[13];
    const float* loc_b1 = (const float*)d_in[14];
    const float* loc_w2 = (const float*)d_in[15];
    const float* loc_b2 = (const float*)d_in[16];
    const float* loc_w3 = (const float*)d_in[17];
    const float* loc_b3 = (const float*)d_in[18];
    float* out = (float*)d_out;

    // ---- Workspace layout (floats), peak 39,845,888 floats = 152 MB ----
    // Liveness-based overlays:
    //   S region (16,777,216 fl): P/E2/E3 (encoder+dec2)  ->  D1  ->  H1/H2
    //   E1 region (16,777,216 fl): E1 (until dec1)        ->  FEAT
    float* ws = (float*)d_ws;
    float* XT = ws;                          //  6,291,456  [2048,3,32,32]
    float* E1 = XT + 6291456;                // 16,777,216  [2048,8,32,32]
    float* S  = E1 + 16777216;               // 16,777,216  shared region
    float* P  = S;                           //  4,194,304  pool scratch
    float* E2 = S + 4194304;                 //  8,388,608  [2048,16,16,16]
    float* E3 = S + 4194304 + 8388608;       //  4,194,304  [2048,32,8,8]
    float* D2 = S + 16777216;                //  8,388,608  [2048,16,16,16]
    float* D1 = S;                           // 16,777,216  (P/E2/E3 dead)
    float* FEAT = E1;                        // 12,582,912  (E1 dead)
    float* H1 = S;                           //    409,600  (D1 dead)
    float* H2 = S + 409600;                  //    409,600
    (void)ws_size; (void)in_sizes; (void)n_in; (void)out_size;

    transpose_kernel<<<Bc * Cc * Hc, 256, 0, stream>>>(x, XT);

    // encoder
    conv3x3_kernel<3, 0, 8, 32, 32, false, true><<<16777216 / 256, 256, 0, stream>>>(
        XT, nullptr, enc_w1, enc_b1, E1);
    pool2_kernel<8, 32, 32><<<4194304 / 256, 256, 0, stream>>>(E1, P);
    conv3x3_kernel<8, 0, 16, 16, 16, false, true><<<8388608 / 256, 256, 0, stream>>>(
        P, nullptr, enc_w2, enc_b2, E2);
    pool2_kernel<16, 16, 16><<<2097152 / 256, 256, 0, stream>>>(E2, P);
    conv3x3_kernel<16, 0, 32, 8, 8, false, true><<<4194304 / 256, 256, 0, stream>>>(
        P, nullptr, enc_w3, enc_b3, E3);

    // decoder (implicit concat [up(deep), skip])
    conv3x3_kernel<32, 16, 16, 16, 16, true, true><<<8388608 / 256, 256, 0, stream>>>(
        E3, E2, dec_w2, dec_b2, D2);
    conv3x3_kernel<16, 8, 8, 32, 32, true, true><<<16777216 / 256, 256, 0, stream>>>(
        D2, E1, dec_w1, dec_b1, D1);

    // 1x1 conv + softmax(+ones) + mask*x -> feat
    maskfeat_kernel<<<2097152 / 256, 256, 0, stream>>>(D1, XT, out_w, out_b, FEAT);

    // LocationNetwork
    fc_relu_kernel<4><<<F / 4, 256, 0, stream>>>(FEAT, loc_w1, loc_b1, H1, FEATN, HID);
    fc_relu_kernel<4><<<F / 4, 256, 0, stream>>>(H1, loc_w2, loc_b2, H2, HID, HID);
    fc3_tanh_kernel<<<F * 4 / 256, 256, 0, stream>>>(H2, loc_w3, loc_b3, out);
}

// Round 7
// 1609.866 us; speedup vs baseline: 3.5747x; 3.5747x over previous
//
#include <hip/hip_runtime.h>

// Problem constants
constexpr int Bc = 32, Tc = 64, Cc = 3, Hc = 32, Wc = 32;
constexpr int F = Bc * Tc;              // 2048 frames
constexpr int FEATN = 2 * Cc * Hc * Wc; // 6144
constexpr int HID = 200;

// ---------------------------------------------------------------------------
// Transpose [B,C,H,W,T] -> [B*T, C, H, W]   (frame f = b*T + t)
// ---------------------------------------------------------------------------
__global__ __launch_bounds__(256)
void transpose_kernel(const float* __restrict__ x, float* __restrict__ xt) {
    __shared__ float lds[32 * 65];
    int bid = blockIdx.x;                 // ((b*3 + c)*32 + h)
    int h = bid & 31;
    int c = (bid >> 5) % 3;
    int b = bid / (3 * 32);
    const float* src = x + (size_t)bid * 2048;   // [w][t] tile, contiguous
#pragma unroll
    for (int j = 0; j < 8; ++j) {
        int i = threadIdx.x + j * 256;           // i = w*64 + t
        lds[(i >> 6) * 65 + (i & 63)] = src[i];
    }
    __syncthreads();
#pragma unroll
    for (int j = 0; j < 8; ++j) {
        int i = threadIdx.x + j * 256;           // i = t*32 + w
        int t = i >> 5, w = i & 31;
        int f = b * 64 + t;
        xt[((size_t)(f * 3 + c) << 10) + h * 32 + w] = lds[w * 65 + t];
    }
}

// ---------------------------------------------------------------------------
// conv3x3_allco: one thread = one pixel x 8 output channels (acc[8]).
// Input loads amortized over 8 outputs; weights in LDS transposed to
// [(ci,kh,kw)][co] so 8 weights = 2x ds_read_b128 at a wave-uniform address
// (broadcast, conflict-free). SAME padding, optional dual input (implicit
// concat [in1(optionally 2x-upsampled), in2]).  w: [COUT,CTOT,3,3] OIHW.
// Thread map: tid = ((f*NCOG + cog)*H + y)*W + x; wave-uniform (f,cog).
// ---------------------------------------------------------------------------
template<int CIN1, int CIN2, int COUT, int H, int W, bool UP1, bool RELU>
__global__ __launch_bounds__(256)
void conv3x3_allco_kernel(const float* __restrict__ in1, const float* __restrict__ in2,
                          const float* __restrict__ wgt, const float* __restrict__ bias,
                          float* __restrict__ out) {
    constexpr int CTOT = CIN1 + CIN2;
    constexpr int NW = CTOT * 9 * COUT;      // [r=(ci,kh,kw)][co]
    constexpr int NCOG = COUT / 8;
    static_assert(COUT % 8 == 0, "COUT % 8");
    __shared__ __align__(16) float wl[NW];
    for (int i = threadIdx.x; i < NW; i += 256) {
        int co = i % COUT, r = i / COUT;
        wl[i] = wgt[co * CTOT * 9 + r];      // transpose OIHW -> [r][co]
    }
    __syncthreads();

    int tid = blockIdx.x * 256 + threadIdx.x;
    int x0  = tid % W;
    int y0  = (tid / W) % H;
    int cog = (tid / (W * H)) % NCOG;
    int f   = tid / (W * H * NCOG);

    float acc[8];
#pragma unroll
    for (int c = 0; c < 8; ++c) acc[c] = bias[cog * 8 + c];

    const float4* wl4 = reinterpret_cast<const float4*>(wl);
    const int wsel = cog * 2;                // float4 offset within a [co] row

    // ---- input1 channels (optionally upsampled) ----
    for (int ci = 0; ci < CIN1; ++ci) {
        const float* ib;
        if (UP1) ib = in1 + (size_t)(f * CIN1 + ci) * (H / 2) * (W / 2);
        else     ib = in1 + (size_t)(f * CIN1 + ci) * H * W;
#pragma unroll
        for (int kh = 0; kh < 3; ++kh) {
            int yy = y0 + kh - 1;
            if (yy < 0 || yy >= H) continue;
#pragma unroll
            for (int kw = 0; kw < 3; ++kw) {
                int xx = x0 + kw - 1;
                if (xx < 0 || xx >= W) continue;
                float v;
                if (UP1) v = ib[(yy >> 1) * (W / 2) + (xx >> 1)];
                else     v = ib[yy * W + xx];
                int r = ci * 9 + kh * 3 + kw;
                float4 w0 = wl4[r * (COUT / 4) + wsel];
                float4 w1 = wl4[r * (COUT / 4) + wsel + 1];
                acc[0] = fmaf(v, w0.x, acc[0]); acc[1] = fmaf(v, w0.y, acc[1]);
                acc[2] = fmaf(v, w0.z, acc[2]); acc[3] = fmaf(v, w0.w, acc[3]);
                acc[4] = fmaf(v, w1.x, acc[4]); acc[5] = fmaf(v, w1.y, acc[5]);
                acc[6] = fmaf(v, w1.z, acc[6]); acc[7] = fmaf(v, w1.w, acc[7]);
            }
        }
    }
    // ---- input2 channels (skip connection, full resolution) ----
    if constexpr (CIN2 > 0) {
        for (int ci2 = 0; ci2 < CIN2; ++ci2) {
            const float* ib = in2 + (size_t)(f * CIN2 + ci2) * H * W;
#pragma unroll
            for (int kh = 0; kh < 3; ++kh) {
                int yy = y0 + kh - 1;
                if (yy < 0 || yy >= H) continue;
#pragma unroll
                for (int kw = 0; kw < 3; ++kw) {
                    int xx = x0 + kw - 1;
                    if (xx < 0 || xx >= W) continue;
                    float v = ib[yy * W + xx];
                    int r = (CIN1 + ci2) * 9 + kh * 3 + kw;
                    float4 w0 = wl4[r * (COUT / 4) + wsel];
                    float4 w1 = wl4[r * (COUT / 4) + wsel + 1];
                    acc[0] = fmaf(v, w0.x, acc[0]); acc[1] = fmaf(v, w0.y, acc[1]);
                    acc[2] = fmaf(v, w0.z, acc[2]); acc[3] = fmaf(v, w0.w, acc[3]);
                    acc[4] = fmaf(v, w1.x, acc[4]); acc[5] = fmaf(v, w1.y, acc[5]);
                    acc[6] = fmaf(v, w1.z, acc[6]); acc[7] = fmaf(v, w1.w, acc[7]);
                }
            }
        }
    }

    size_t ob = (size_t)(f * COUT + cog * 8) * (H * W) + y0 * W + x0;
#pragma unroll
    for (int c = 0; c < 8; ++c) {
        float vv = acc[c];
        if (RELU) vv = fmaxf(vv, 0.0f);
        out[ob + (size_t)c * (H * W)] = vv;
    }
}

// ---------------------------------------------------------------------------
// 2x2 max pool, stride 2
// ---------------------------------------------------------------------------
template<int CH, int H, int W>
__global__ __launch_bounds__(256)
void pool2_kernel(const float* __restrict__ in, float* __restrict__ out) {
    int tid = blockIdx.x * 256 + threadIdx.x;
    constexpr int total = F * CH * (H / 2) * (W / 2);
    if (tid >= total) return;
    int x = tid % (W / 2);
    int y = (tid / (W / 2)) % (H / 2);
    int fc = tid / ((W / 2) * (H / 2));   // f*CH + c
    const float* ib = in + (size_t)fc * H * W + (2 * y) * W + 2 * x;
    float m = fmaxf(fmaxf(ib[0], ib[1]), fmaxf(ib[W], ib[W + 1]));
    out[tid] = m;
}

// ---------------------------------------------------------------------------
// 1x1 out-conv (8->2) + softmax over [l0, l1, 1] + mask*x -> feat [F, 6144]
// ---------------------------------------------------------------------------
__global__ __launch_bounds__(256)
void maskfeat_kernel(const float* __restrict__ d1, const float* __restrict__ xt,
                     const float* __restrict__ ow, const float* __restrict__ ob,
                     float* __restrict__ feat) {
    int tid = blockIdx.x * 256 + threadIdx.x;
    if (tid >= F * 1024) return;
    int hw = tid & 1023;
    int f  = tid >> 10;
    const float* db = d1 + ((size_t)f << 13) + hw;   // f*8*1024
    float l0 = ob[0], l1 = ob[1];
#pragma unroll
    for (int c = 0; c < 8; ++c) {
        float v = db[c << 10];
        l0 = fmaf(v, ow[c], l0);
        l1 = fmaf(v, ow[8 + c], l1);
    }
    float mx = fmaxf(fmaxf(l0, l1), 1.0f);
    float e0 = expf(l0 - mx), e1 = expf(l1 - mx), e2 = expf(1.0f - mx);
    float inv = 1.0f / (e0 + e1 + e2);
    float m0 = e0 * inv, m1 = e1 * inv;
    const float* xb = xt + (size_t)f * 3072 + hw;
    float* fb = feat + (size_t)f * 6144 + hw;
#pragma unroll
    for (int c = 0; c < 3; ++c) {
        float xv = xb[c << 10];
        fb[c << 10]          = m0 * xv;
        fb[3072 + (c << 10)] = m1 * xv;
    }
}

// ---------------------------------------------------------------------------
// Register-tiled FC (+ReLU): out[F,200] = relu(A[F,K] @ W[K,200] + b)
// Block: BM=8 rows x 200 cols. Active threads (t<200): tx=t%25 -> 8 contiguous
// cols (two float4 W loads per k, coalesced, L2-resident); ty=t/25 -> row.
// A tile staged in LDS (broadcast reads). BK unrolled for ILP.
// ---------------------------------------------------------------------------
template<int K, int BK>
__global__ __launch_bounds__(256)
void fc_tiled_kernel(const float* __restrict__ A, const float* __restrict__ Wm,
                     const float* __restrict__ bias, float* __restrict__ out) {
    constexpr int BM = 8, N = 200;
    static_assert(K % BK == 0, "K % BK");
    __shared__ float As[BM * BK];
    int t = threadIdx.x;
    int row0 = blockIdx.x * BM;
    int tx = t % 25, ty = t / 25;
    bool active = (ty < BM);
    int c0 = tx * 8;
    float acc0 = 0.f, acc1 = 0.f, acc2 = 0.f, acc3 = 0.f;
    float acc4 = 0.f, acc5 = 0.f, acc6 = 0.f, acc7 = 0.f;

    for (int kb = 0; kb < K; kb += BK) {
        for (int i = t; i < BM * BK; i += 256) {
            int r = i / BK, kk = i % BK;
            As[i] = A[(size_t)(row0 + r) * K + kb + kk];
        }
        __syncthreads();
        if (active) {
#pragma unroll
            for (int kk = 0; kk < BK; ++kk) {
                float a = As[ty * BK + kk];
                const float4* wp =
                    reinterpret_cast<const float4*>(Wm + (size_t)(kb + kk) * N + c0);
                float4 w0 = wp[0], w1 = wp[1];
                acc0 = fmaf(a, w0.x, acc0); acc1 = fmaf(a, w0.y, acc1);
                acc2 = fmaf(a, w0.z, acc2); acc3 = fmaf(a, w0.w, acc3);
                acc4 = fmaf(a, w1.x, acc4); acc5 = fmaf(a, w1.y, acc5);
                acc6 = fmaf(a, w1.z, acc6); acc7 = fmaf(a, w1.w, acc7);
            }
        }
        __syncthreads();
    }
    if (active) {
        const float4* bp = reinterpret_cast<const float4*>(bias + c0);
        float4 b0 = bp[0], b1 = bp[1];
        float4 o0, o1;
        o0.x = fmaxf(acc0 + b0.x, 0.f); o0.y = fmaxf(acc1 + b0.y, 0.f);
        o0.z = fmaxf(acc2 + b0.z, 0.f); o0.w = fmaxf(acc3 + b0.w, 0.f);
        o1.x = fmaxf(acc4 + b1.x, 0.f); o1.y = fmaxf(acc5 + b1.y, 0.f);
        o1.z = fmaxf(acc6 + b1.z, 0.f); o1.w = fmaxf(acc7 + b1.w, 0.f);
        float4* op = reinterpret_cast<float4*>(out + (size_t)(row0 + ty) * N + c0);
        op[0] = o0; op[1] = o1;
    }
}

// ---------------------------------------------------------------------------
// FC3 (200 -> 4) + tanh epilogue: one thread per frame, W3 staged in LDS.
// ---------------------------------------------------------------------------
__global__ __launch_bounds__(256)
void fc3_tanh_kernel(const float* __restrict__ A, const float* __restrict__ Wm,
                     const float* __restrict__ bias, float* __restrict__ out) {
    __shared__ float wl[800];
    int t = threadIdx.x;
#pragma unroll
    for (int j = 0; j < 4; ++j) {
        int i = t + j * 256;
        if (i < 800) wl[i] = Wm[i];
    }
    __syncthreads();
    int row = blockIdx.x * 256 + t;
    float a0 = bias[0], a1 = bias[1], a2 = bias[2], a3 = bias[3];
    const float* ar = A + (size_t)row * 200;
#pragma unroll 8
    for (int k = 0; k < 200; ++k) {
        float a = ar[k];
        const float4 w = *reinterpret_cast<const float4*>(&wl[k * 4]);
        a0 = fmaf(a, w.x, a0); a1 = fmaf(a, w.y, a1);
        a2 = fmaf(a, w.z, a2); a3 = fmaf(a, w.w, a3);
    }
    float4 o;
    o.x = tanhf(a0) * 16.0f + 16.0f;
    o.y = tanhf(a1) * 16.0f + 16.0f;
    o.z = tanhf(a2) * 16.0f + 16.0f;
    o.w = tanhf(a3) * 16.0f + 16.0f;
    *reinterpret_cast<float4*>(out + (size_t)row * 4) = o;
}

// ---------------------------------------------------------------------------
extern "C" void kernel_launch(void* const* d_in, const int* in_sizes, int n_in,
                              void* d_out, int out_size, void* d_ws, size_t ws_size,
                              hipStream_t stream) {
    const float* x      = (const float*)d_in[0];
    const float* enc_w1 = (const float*)d_in[1];
    const float* enc_b1 = (const float*)d_in[2];
    const float* enc_w2 = (const float*)d_in[3];
    const float* enc_b2 = (const float*)d_in[4];
    const float* enc_w3 = (const float*)d_in[5];
    const float* enc_b3 = (const float*)d_in[6];
    const float* dec_w2 = (const float*)d_in[7];
    const float* dec_b2 = (const float*)d_in[8];
    const float* dec_w1 = (const float*)d_in[9];
    const float* dec_b1 = (const float*)d_in[10];
    const float* out_w  = (const float*)d_in[11];
    const float* out_b  = (const float*)d_in[12];
    const float* loc_w1 = (const float*)d_in[13];
    const float* loc_b1 = (const float*)d_in[14];
    const float* loc_w2 = (const float*)d_in[15];
    const float* loc_b2 = (const float*)d_in[16];
    const float* loc_w3 = (const float*)d_in[17];
    const float* loc_b3 = (const float*)d_in[18];
    float* out = (float*)d_out;

    // ---- Workspace layout (floats), peak 39,845,888 floats = 152 MB ----
    // Liveness overlays:
    //   S region: P/E2/E3 (encoder+dec2) -> D1 -> H1/H2
    //   E1 region: E1 (until dec1) -> FEAT
    float* ws = (float*)d_ws;
    float* XT = ws;                          //  6,291,456  [2048,3,32,32]
    float* E1 = XT + 6291456;                // 16,777,216  [2048,8,32,32]
    float* S  = E1 + 16777216;               // 16,777,216  shared region
    float* P  = S;                           //  4,194,304  pool scratch
    float* E2 = S + 4194304;                 //  8,388,608  [2048,16,16,16]
    float* E3 = S + 4194304 + 8388608;       //  4,194,304  [2048,32,8,8]
    float* D2 = S + 16777216;                //  8,388,608  [2048,16,16,16]
    float* D1 = S;                           // 16,777,216  (P/E2/E3 dead)
    float* FEAT = E1;                        // 12,582,912  (E1 dead)
    float* H1 = S;                           //    409,600  (D1 dead)
    float* H2 = S + 409600;                  //    409,600
    (void)ws_size; (void)in_sizes; (void)n_in; (void)out_size;

    transpose_kernel<<<Bc * Cc * Hc, 256, 0, stream>>>(x, XT);

    // encoder (grid = F * (COUT/8) * H*W / 256, all exact multiples)
    conv3x3_allco_kernel<3, 0, 8, 32, 32, false, true><<<8192, 256, 0, stream>>>(
        XT, nullptr, enc_w1, enc_b1, E1);
    pool2_kernel<8, 32, 32><<<4194304 / 256, 256, 0, stream>>>(E1, P);
    conv3x3_allco_kernel<8, 0, 16, 16, 16, false, true><<<4096, 256, 0, stream>>>(
        P, nullptr, enc_w2, enc_b2, E2);
    pool2_kernel<16, 16, 16><<<2097152 / 256, 256, 0, stream>>>(E2, P);
    conv3x3_allco_kernel<16, 0, 32, 8, 8, false, true><<<2048, 256, 0, stream>>>(
        P, nullptr, enc_w3, enc_b3, E3);

    // decoder (implicit concat [up(deep), skip])
    conv3x3_allco_kernel<32, 16, 16, 16, 16, true, true><<<4096, 256, 0, stream>>>(
        E3, E2, dec_w2, dec_b2, D2);
    conv3x3_allco_kernel<16, 8, 8, 32, 32, true, true><<<8192, 256, 0, stream>>>(
        D2, E1, dec_w1, dec_b1, D1);

    // 1x1 conv + softmax(+ones) + mask*x -> feat
    maskfeat_kernel<<<2097152 / 256, 256, 0, stream>>>(D1, XT, out_w, out_b, FEAT);

    // LocationNetwork (register-tiled GEMMs)
    fc_tiled_kernel<FEATN, 32><<<F / 8, 256, 0, stream>>>(FEAT, loc_w1, loc_b1, H1);
    fc_tiled_kernel<HID, 40><<<F / 8, 256, 0, stream>>>(H1, loc_w2, loc_b2, H2);
    fc3_tanh_kernel<<<F / 256, 256, 0, stream>>>(H2, loc_w3, loc_b3, out);
}

// Round 8
// 942.573 us; speedup vs baseline: 6.1055x; 1.7079x over previous
//
#include <hip/hip_runtime.h>

// Problem constants
constexpr int Bc = 32, Tc = 64, Cc = 3, Hc = 32, Wc = 32;
constexpr int F = Bc * Tc;              // 2048 frames
constexpr int FEATN = 2 * Cc * Hc * Wc; // 6144
constexpr int HID = 200;
constexpr int NP = 224;                 // padded N for FC1 (7 x 32)
constexpr int KSPLIT = 16;              // K chunks of 384

typedef __attribute__((ext_vector_type(8))) short bf16x8;
typedef __attribute__((ext_vector_type(4))) float f32x4;

static __device__ __forceinline__ ushort f2bf(float x) {
    union { float f; unsigned u; } v; v.f = x;
    unsigned r = (v.u + 0x7FFF + ((v.u >> 16) & 1)) >> 16;   // RNE
    return (ushort)r;
}

// ---------------------------------------------------------------------------
// Transpose [B,C,H,W,T] -> [B*T, C, H, W]   (frame f = b*T + t)
// ---------------------------------------------------------------------------
__global__ __launch_bounds__(256)
void transpose_kernel(const float* __restrict__ x, float* __restrict__ xt) {
    __shared__ float lds[32 * 65];
    int bid = blockIdx.x;                 // ((b*3 + c)*32 + h)
    int h = bid & 31;
    int c = (bid >> 5) % 3;
    int b = bid / (3 * 32);
    const float* src = x + (size_t)bid * 2048;   // [w][t] tile, contiguous
#pragma unroll
    for (int j = 0; j < 8; ++j) {
        int i = threadIdx.x + j * 256;           // i = w*64 + t
        lds[(i >> 6) * 65 + (i & 63)] = src[i];
    }
    __syncthreads();
#pragma unroll
    for (int j = 0; j < 8; ++j) {
        int i = threadIdx.x + j * 256;           // i = t*32 + w
        int t = i >> 5, w = i & 31;
        int f = b * 64 + t;
        xt[((size_t)(f * 3 + c) << 10) + h * 32 + w] = lds[w * 65 + t];
    }
}

// ---------------------------------------------------------------------------
// conv3x3_allco: one thread = one pixel x 8 output channels (acc[8]).
// Weights in LDS transposed to [(ci,kh,kw)][co]; wave-uniform (f,cog).
// ---------------------------------------------------------------------------
template<int CIN1, int CIN2, int COUT, int H, int W, bool UP1, bool RELU>
__global__ __launch_bounds__(256)
void conv3x3_allco_kernel(const float* __restrict__ in1, const float* __restrict__ in2,
                          const float* __restrict__ wgt, const float* __restrict__ bias,
                          float* __restrict__ out) {
    constexpr int CTOT = CIN1 + CIN2;
    constexpr int NW = CTOT * 9 * COUT;      // [r=(ci,kh,kw)][co]
    constexpr int NCOG = COUT / 8;
    static_assert(COUT % 8 == 0, "COUT % 8");
    __shared__ __align__(16) float wl[NW];
    for (int i = threadIdx.x; i < NW; i += 256) {
        int co = i % COUT, r = i / COUT;
        wl[i] = wgt[co * CTOT * 9 + r];      // transpose OIHW -> [r][co]
    }
    __syncthreads();

    int tid = blockIdx.x * 256 + threadIdx.x;
    int x0  = tid % W;
    int y0  = (tid / W) % H;
    int cog = (tid / (W * H)) % NCOG;
    int f   = tid / (W * H * NCOG);

    float acc[8];
#pragma unroll
    for (int c = 0; c < 8; ++c) acc[c] = bias[cog * 8 + c];

    const float4* wl4 = reinterpret_cast<const float4*>(wl);
    const int wsel = cog * 2;

    for (int ci = 0; ci < CIN1; ++ci) {
        const float* ib;
        if (UP1) ib = in1 + (size_t)(f * CIN1 + ci) * (H / 2) * (W / 2);
        else     ib = in1 + (size_t)(f * CIN1 + ci) * H * W;
#pragma unroll
        for (int kh = 0; kh < 3; ++kh) {
            int yy = y0 + kh - 1;
            if (yy < 0 || yy >= H) continue;
#pragma unroll
            for (int kw = 0; kw < 3; ++kw) {
                int xx = x0 + kw - 1;
                if (xx < 0 || xx >= W) continue;
                float v;
                if (UP1) v = ib[(yy >> 1) * (W / 2) + (xx >> 1)];
                else     v = ib[yy * W + xx];
                int r = ci * 9 + kh * 3 + kw;
                float4 w0 = wl4[r * (COUT / 4) + wsel];
                float4 w1 = wl4[r * (COUT / 4) + wsel + 1];
                acc[0] = fmaf(v, w0.x, acc[0]); acc[1] = fmaf(v, w0.y, acc[1]);
                acc[2] = fmaf(v, w0.z, acc[2]); acc[3] = fmaf(v, w0.w, acc[3]);
                acc[4] = fmaf(v, w1.x, acc[4]); acc[5] = fmaf(v, w1.y, acc[5]);
                acc[6] = fmaf(v, w1.z, acc[6]); acc[7] = fmaf(v, w1.w, acc[7]);
            }
        }
    }
    if constexpr (CIN2 > 0) {
        for (int ci2 = 0; ci2 < CIN2; ++ci2) {
            const float* ib = in2 + (size_t)(f * CIN2 + ci2) * H * W;
#pragma unroll
            for (int kh = 0; kh < 3; ++kh) {
                int yy = y0 + kh - 1;
                if (yy < 0 || yy >= H) continue;
#pragma unroll
                for (int kw = 0; kw < 3; ++kw) {
                    int xx = x0 + kw - 1;
                    if (xx < 0 || xx >= W) continue;
                    float v = ib[yy * W + xx];
                    int r = (CIN1 + ci2) * 9 + kh * 3 + kw;
                    float4 w0 = wl4[r * (COUT / 4) + wsel];
                    float4 w1 = wl4[r * (COUT / 4) + wsel + 1];
                    acc[0] = fmaf(v, w0.x, acc[0]); acc[1] = fmaf(v, w0.y, acc[1]);
                    acc[2] = fmaf(v, w0.z, acc[2]); acc[3] = fmaf(v, w0.w, acc[3]);
                    acc[4] = fmaf(v, w1.x, acc[4]); acc[5] = fmaf(v, w1.y, acc[5]);
                    acc[6] = fmaf(v, w1.z, acc[6]); acc[7] = fmaf(v, w1.w, acc[7]);
                }
            }
        }
    }

    size_t ob = (size_t)(f * COUT + cog * 8) * (H * W) + y0 * W + x0;
#pragma unroll
    for (int c = 0; c < 8; ++c) {
        float vv = acc[c];
        if (RELU) vv = fmaxf(vv, 0.0f);
        out[ob + (size_t)c * (H * W)] = vv;
    }
}

// ---------------------------------------------------------------------------
// 2x2 max pool, stride 2
// ---------------------------------------------------------------------------
template<int CH, int H, int W>
__global__ __launch_bounds__(256)
void pool2_kernel(const float* __restrict__ in, float* __restrict__ out) {
    int tid = blockIdx.x * 256 + threadIdx.x;
    constexpr int total = F * CH * (H / 2) * (W / 2);
    if (tid >= total) return;
    int x = tid % (W / 2);
    int y = (tid / (W / 2)) % (H / 2);
    int fc = tid / ((W / 2) * (H / 2));   // f*CH + c
    const float* ib = in + (size_t)fc * H * W + (2 * y) * W + 2 * x;
    float m = fmaxf(fmaxf(ib[0], ib[1]), fmaxf(ib[W], ib[W + 1]));
    out[tid] = m;
}

// ---------------------------------------------------------------------------
// 1x1 out-conv (8->2) + softmax over [l0, l1, 1] + mask*x -> feat bf16 [F,6144]
// ---------------------------------------------------------------------------
__global__ __launch_bounds__(256)
void maskfeat_kernel(const float* __restrict__ d1, const float* __restrict__ xt,
                     const float* __restrict__ ow, const float* __restrict__ ob,
                     ushort* __restrict__ feat) {
    int tid = blockIdx.x * 256 + threadIdx.x;
    if (tid >= F * 1024) return;
    int hw = tid & 1023;
    int f  = tid >> 10;
    const float* db = d1 + ((size_t)f << 13) + hw;   // f*8*1024
    float l0 = ob[0], l1 = ob[1];
#pragma unroll
    for (int c = 0; c < 8; ++c) {
        float v = db[c << 10];
        l0 = fmaf(v, ow[c], l0);
        l1 = fmaf(v, ow[8 + c], l1);
    }
    float mx = fmaxf(fmaxf(l0, l1), 1.0f);
    float e0 = expf(l0 - mx), e1 = expf(l1 - mx), e2 = expf(1.0f - mx);
    float inv = 1.0f / (e0 + e1 + e2);
    float m0 = e0 * inv, m1 = e1 * inv;
    const float* xb = xt + (size_t)f * 3072 + hw;
    ushort* fb = feat + (size_t)f * 6144 + hw;
#pragma unroll
    for (int c = 0; c < 3; ++c) {
        float xv = xb[c << 10];
        fb[c << 10]          = f2bf(m0 * xv);
        fb[3072 + (c << 10)] = f2bf(m1 * xv);
    }
}

// ---------------------------------------------------------------------------
// W1 prep: W1[6144][200] fp32 -> BT[224][6144] bf16 (pad n>=200 with 0).
// 32x32 LDS tile transpose; grid = 192 k-tiles x 7 n-tiles.
// ---------------------------------------------------------------------------
__global__ __launch_bounds__(256)
void w1prep_kernel(const float* __restrict__ W, ushort* __restrict__ BT) {
    __shared__ float t[32][33];
    int kb = blockIdx.x % 192, nb = blockIdx.x / 192;
    int k0 = kb * 32, n0 = nb * 32;
    int r = threadIdx.x / 32, c = threadIdx.x % 32;
#pragma unroll
    for (int p = 0; p < 4; ++p) {
        int kk = r + p * 8;
        int n = n0 + c;
        t[kk][c] = (n < 200) ? W[(size_t)(k0 + kk) * 200 + n] : 0.0f;
    }
    __syncthreads();
#pragma unroll
    for (int p = 0; p < 4; ++p) {
        int nn = r + p * 8;
        BT[(size_t)(n0 + nn) * 6144 + k0 + c] = f2bf(t[c][nn]);
    }
}

// ---------------------------------------------------------------------------
// FC1 MFMA: P[kc][2048][224] partial = A[2048][6144]bf16 x BT^T, K-chunk 384.
// Wave tile 64M x 32N; 2 waves/block; grid 16M x 7N x 16K = 1792 blocks.
// Fragment layouts (m89-verified): A lane: row=l%16, k=(l/16)*8+j;
// B lane: col=l%16 (BT row), k=(l/16)*8+j; D: col=l&15, row=(l>>4)*4+reg.
// ---------------------------------------------------------------------------
__global__ __launch_bounds__(128)
void fc1_mfma_kernel(const ushort* __restrict__ A, const ushort* __restrict__ BT,
                     float* __restrict__ P) {
    int bid = blockIdx.x;
    int mb = bid & 15;
    int nb = (bid >> 4) % 7;
    int kc = bid / (16 * 7);
    int w = threadIdx.x >> 6, lane = threadIdx.x & 63;
    int m0 = mb * 128 + w * 64;
    int n0 = nb * 32;
    int row16 = lane & 15, kgrp = lane >> 4;

    f32x4 acc00 = {0,0,0,0}, acc01 = {0,0,0,0}, acc10 = {0,0,0,0}, acc11 = {0,0,0,0};
    f32x4 acc20 = {0,0,0,0}, acc21 = {0,0,0,0}, acc30 = {0,0,0,0}, acc31 = {0,0,0,0};

    const ushort* aB = A  + (size_t)(m0 + row16) * 6144 + kgrp * 8;
    const ushort* bB = BT + (size_t)(n0 + row16) * 6144 + kgrp * 8;
    int kend = kc * 384 + 384;
    for (int k = kc * 384; k < kend; k += 32) {
        bf16x8 b0 = *(const bf16x8*)(bB + k);
        bf16x8 b1 = *(const bf16x8*)(bB + 16 * 6144 + k);
        bf16x8 a0 = *(const bf16x8*)(aB + k);
        bf16x8 a1 = *(const bf16x8*)(aB + 16 * 6144 + k);
        bf16x8 a2 = *(const bf16x8*)(aB + 32 * 6144 + k);
        bf16x8 a3 = *(const bf16x8*)(aB + 48 * 6144 + k);
        acc00 = __builtin_amdgcn_mfma_f32_16x16x32_bf16(a0, b0, acc00, 0, 0, 0);
        acc01 = __builtin_amdgcn_mfma_f32_16x16x32_bf16(a0, b1, acc01, 0, 0, 0);
        acc10 = __builtin_amdgcn_mfma_f32_16x16x32_bf16(a1, b0, acc10, 0, 0, 0);
        acc11 = __builtin_amdgcn_mfma_f32_16x16x32_bf16(a1, b1, acc11, 0, 0, 0);
        acc20 = __builtin_amdgcn_mfma_f32_16x16x32_bf16(a2, b0, acc20, 0, 0, 0);
        acc21 = __builtin_amdgcn_mfma_f32_16x16x32_bf16(a2, b1, acc21, 0, 0, 0);
        acc30 = __builtin_amdgcn_mfma_f32_16x16x32_bf16(a3, b0, acc30, 0, 0, 0);
        acc31 = __builtin_amdgcn_mfma_f32_16x16x32_bf16(a3, b1, acc31, 0, 0, 0);
    }

    float* Pb = P + (size_t)kc * 2048 * NP;
    const f32x4* accs[4][2] = {{&acc00,&acc01},{&acc10,&acc11},{&acc20,&acc21},{&acc30,&acc31}};
#pragma unroll
    for (int s = 0; s < 4; ++s) {
#pragma unroll
        for (int h = 0; h < 2; ++h) {
            const f32x4 v = *accs[s][h];
#pragma unroll
            for (int r = 0; r < 4; ++r) {
                int m = m0 + s * 16 + kgrp * 4 + r;
                int n = n0 + h * 16 + row16;
                Pb[(size_t)m * NP + n] = v[r];
            }
        }
    }
}

// ---------------------------------------------------------------------------
// FC1 reduce: H1[m][n] = relu(bias[n] + sum_kc P[kc][m][n]), n < 200
// ---------------------------------------------------------------------------
__global__ __launch_bounds__(256)
void fc1_reduce_kernel(const float* __restrict__ P, const float* __restrict__ bias,
                       float* __restrict__ H1) {
    int tid = blockIdx.x * 256 + threadIdx.x;
    if (tid >= F * 200) return;
    int n = tid % 200, m = tid / 200;
    float s = bias[n];
#pragma unroll
    for (int kc = 0; kc < KSPLIT; ++kc)
        s += P[((size_t)kc * 2048 + m) * NP + n];
    H1[(size_t)m * 200 + n] = fmaxf(s, 0.0f);
}

// ---------------------------------------------------------------------------
// Register-tiled FC (+ReLU): out[F,200] = relu(A[F,K] @ W[K,200] + b)
// ---------------------------------------------------------------------------
template<int K, int BK>
__global__ __launch_bounds__(256)
void fc_tiled_kernel(const float* __restrict__ A, const float* __restrict__ Wm,
                     const float* __restrict__ bias, float* __restrict__ out) {
    constexpr int BM = 8, N = 200;
    static_assert(K % BK == 0, "K % BK");
    __shared__ float As[BM * BK];
    int t = threadIdx.x;
    int row0 = blockIdx.x * BM;
    int tx = t % 25, ty = t / 25;
    bool active = (ty < BM);
    int c0 = tx * 8;
    float acc0 = 0.f, acc1 = 0.f, acc2 = 0.f, acc3 = 0.f;
    float acc4 = 0.f, acc5 = 0.f, acc6 = 0.f, acc7 = 0.f;

    for (int kb = 0; kb < K; kb += BK) {
        for (int i = t; i < BM * BK; i += 256) {
            int r = i / BK, kk = i % BK;
            As[i] = A[(size_t)(row0 + r) * K + kb + kk];
        }
        __syncthreads();
        if (active) {
#pragma unroll
            for (int kk = 0; kk < BK; ++kk) {
                float a = As[ty * BK + kk];
                const float4* wp =
                    reinterpret_cast<const float4*>(Wm + (size_t)(kb + kk) * N + c0);
                float4 w0 = wp[0], w1 = wp[1];
                acc0 = fmaf(a, w0.x, acc0); acc1 = fmaf(a, w0.y, acc1);
                acc2 = fmaf(a, w0.z, acc2); acc3 = fmaf(a, w0.w, acc3);
                acc4 = fmaf(a, w1.x, acc4); acc5 = fmaf(a, w1.y, acc5);
                acc6 = fmaf(a, w1.z, acc6); acc7 = fmaf(a, w1.w, acc7);
            }
        }
        __syncthreads();
    }
    if (active) {
        const float4* bp = reinterpret_cast<const float4*>(bias + c0);
        float4 b0 = bp[0], b1 = bp[1];
        float4 o0, o1;
        o0.x = fmaxf(acc0 + b0.x, 0.f); o0.y = fmaxf(acc1 + b0.y, 0.f);
        o0.z = fmaxf(acc2 + b0.z, 0.f); o0.w = fmaxf(acc3 + b0.w, 0.f);
        o1.x = fmaxf(acc4 + b1.x, 0.f); o1.y = fmaxf(acc5 + b1.y, 0.f);
        o1.z = fmaxf(acc6 + b1.z, 0.f); o1.w = fmaxf(acc7 + b1.w, 0.f);
        float4* op = reinterpret_cast<float4*>(out + (size_t)(row0 + ty) * N + c0);
        op[0] = o0; op[1] = o1;
    }
}

// ---------------------------------------------------------------------------
// FC3 (200 -> 4) + tanh epilogue: one thread per frame, W3 staged in LDS.
// ---------------------------------------------------------------------------
__global__ __launch_bounds__(256)
void fc3_tanh_kernel(const float* __restrict__ A, const float* __restrict__ Wm,
                     const float* __restrict__ bias, float* __restrict__ out) {
    __shared__ float wl[800];
    int t = threadIdx.x;
#pragma unroll
    for (int j = 0; j < 4; ++j) {
        int i = t + j * 256;
        if (i < 800) wl[i] = Wm[i];
    }
    __syncthreads();
    int row = blockIdx.x * 256 + t;
    float a0 = bias[0], a1 = bias[1], a2 = bias[2], a3 = bias[3];
    const float* ar = A + (size_t)row * 200;
#pragma unroll 8
    for (int k = 0; k < 200; ++k) {
        float a = ar[k];
        const float4 w = *reinterpret_cast<const float4*>(&wl[k * 4]);
        a0 = fmaf(a, w.x, a0); a1 = fmaf(a, w.y, a1);
        a2 = fmaf(a, w.z, a2); a3 = fmaf(a, w.w, a3);
    }
    float4 o;
    o.x = tanhf(a0) * 16.0f + 16.0f;
    o.y = tanhf(a1) * 16.0f + 16.0f;
    o.z = tanhf(a2) * 16.0f + 16.0f;
    o.w = tanhf(a3) * 16.0f + 16.0f;
    *reinterpret_cast<float4*>(out + (size_t)row * 4) = o;
}

// ---------------------------------------------------------------------------
extern "C" void kernel_launch(void* const* d_in, const int* in_sizes, int n_in,
                              void* d_out, int out_size, void* d_ws, size_t ws_size,
                              hipStream_t stream) {
    const float* x      = (const float*)d_in[0];
    const float* enc_w1 = (const float*)d_in[1];
    const float* enc_b1 = (const float*)d_in[2];
    const float* enc_w2 = (const float*)d_in[3];
    const float* enc_b2 = (const float*)d_in[4];
    const float* enc_w3 = (const float*)d_in[5];
    const float* enc_b3 = (const float*)d_in[6];
    const float* dec_w2 = (const float*)d_in[7];
    const float* dec_b2 = (const float*)d_in[8];
    const float* dec_w1 = (const float*)d_in[9];
    const float* dec_b1 = (const float*)d_in[10];
    const float* out_w  = (const float*)d_in[11];
    const float* out_b  = (const float*)d_in[12];
    const float* loc_w1 = (const float*)d_in[13];
    const float* loc_b1 = (const float*)d_in[14];
    const float* loc_w2 = (const float*)d_in[15];
    const float* loc_b2 = (const float*)d_in[16];
    const float* loc_w3 = (const float*)d_in[17];
    const float* loc_b3 = (const float*)d_in[18];
    float* out = (float*)d_out;

    // ---- Workspace layout (floats), peak 39,845,888 floats = 152 MB ----
    // S region liveness: P/E2/E3 (encoder+dec2) -> D1 -> {H1,H2,P16,BT}
    // E1 region: E1 (until dec1) -> FEATB (bf16)
    float* ws = (float*)d_ws;
    float* XT = ws;                          //  6,291,456  [2048,3,32,32]
    float* E1 = XT + 6291456;                // 16,777,216  [2048,8,32,32]
    float* S  = E1 + 16777216;               // 16,777,216  shared region
    float* P  = S;                           //  4,194,304  pool scratch
    float* E2 = S + 4194304;                 //  8,388,608  [2048,16,16,16]
    float* E3 = S + 4194304 + 8388608;       //  4,194,304  [2048,32,8,8]
    float* D2 = S + 16777216;                //  8,388,608  [2048,16,16,16]
    float* D1 = S;                           // 16,777,216  (P/E2/E3 dead)
    ushort* FEATB = (ushort*)E1;             // 12,582,912 bf16 (E1 dead)
    float* H1 = S;                           //    409,600  (D1 dead)
    float* H2 = S + 409600;                  //    409,600
    float* P16 = S + 819200;                 //  7,340,032  [16,2048,224] fp32
    ushort* BT = (ushort*)(S + 8159232);     //  1,376,256 bf16 [224,6144]
    (void)ws_size; (void)in_sizes; (void)n_in; (void)out_size;

    transpose_kernel<<<Bc * Cc * Hc, 256, 0, stream>>>(x, XT);

    // encoder
    conv3x3_allco_kernel<3, 0, 8, 32, 32, false, true><<<8192, 256, 0, stream>>>(
        XT, nullptr, enc_w1, enc_b1, E1);
    pool2_kernel<8, 32, 32><<<4194304 / 256, 256, 0, stream>>>(E1, P);
    conv3x3_allco_kernel<8, 0, 16, 16, 16, false, true><<<4096, 256, 0, stream>>>(
        P, nullptr, enc_w2, enc_b2, E2);
    pool2_kernel<16, 16, 16><<<2097152 / 256, 256, 0, stream>>>(E2, P);
    conv3x3_allco_kernel<16, 0, 32, 8, 8, false, true><<<2048, 256, 0, stream>>>(
        P, nullptr, enc_w3, enc_b3, E3);

    // decoder (implicit concat [up(deep), skip])
    conv3x3_allco_kernel<32, 16, 16, 16, 16, true, true><<<4096, 256, 0, stream>>>(
        E3, E2, dec_w2, dec_b2, D2);
    conv3x3_allco_kernel<16, 8, 8, 32, 32, true, true><<<8192, 256, 0, stream>>>(
        D2, E1, dec_w1, dec_b1, D1);

    // 1x1 conv + softmax(+ones) + mask*x -> bf16 feat
    maskfeat_kernel<<<2097152 / 256, 256, 0, stream>>>(D1, XT, out_w, out_b, FEATB);

    // LocationNetwork: FC1 via bf16 MFMA split-K
    w1prep_kernel<<<192 * 7, 256, 0, stream>>>(loc_w1, BT);
    fc1_mfma_kernel<<<16 * 7 * KSPLIT, 128, 0, stream>>>(FEATB, BT, P16);
    fc1_reduce_kernel<<<(F * 200 + 255) / 256, 256, 0, stream>>>(P16, loc_b1, H1);
    fc_tiled_kernel<HID, 40><<<F / 8, 256, 0, stream>>>(H1, loc_w2, loc_b2, H2);
    fc3_tanh_kernel<<<F / 256, 256, 0, stream>>>(H2, loc_w3, loc_b3, out);
}

// Round 11
// 617.932 us; speedup vs baseline: 9.3131x; 1.5254x over previous
//
#include <hip/hip_runtime.h>

// Problem constants
constexpr int Bc = 32, Tc = 64, Cc = 3, Hc = 32, Wc = 32;
constexpr int F = Bc * Tc;              // 2048 frames
constexpr int FEATN = 2 * Cc * Hc * Wc; // 6144
constexpr int HID = 200;
constexpr int NP = 224;                 // padded N for FC1 (7 x 32)
constexpr int KSPLIT = 16;              // K chunks of 384

typedef __attribute__((ext_vector_type(8))) short bf16x8;
typedef __attribute__((ext_vector_type(4))) float f32x4;

static __device__ __forceinline__ ushort f2bf(float x) {
    union { float f; unsigned u; } v; v.f = x;
    unsigned r = (v.u + 0x7FFF + ((v.u >> 16) & 1)) >> 16;   // RNE
    return (ushort)r;
}

// ---------------------------------------------------------------------------
// Transpose [B,C,H,W,T] -> [B*T, C, H, W]   (frame f = b*T + t)
// ---------------------------------------------------------------------------
__global__ __launch_bounds__(256)
void transpose_kernel(const float* __restrict__ x, float* __restrict__ xt) {
    __shared__ float lds[32 * 65];
    int bid = blockIdx.x;                 // ((b*3 + c)*32 + h)
    int h = bid & 31;
    int c = (bid >> 5) % 3;
    int b = bid / (3 * 32);
    const float* src = x + (size_t)bid * 2048;   // [w][t] tile, contiguous
#pragma unroll
    for (int j = 0; j < 8; ++j) {
        int i = threadIdx.x + j * 256;           // i = w*64 + t
        lds[(i >> 6) * 65 + (i & 63)] = src[i];
    }
    __syncthreads();
#pragma unroll
    for (int j = 0; j < 8; ++j) {
        int i = threadIdx.x + j * 256;           // i = t*32 + w
        int t = i >> 5, w = i & 31;
        int f = b * 64 + t;
        xt[((size_t)(f * 3 + c) << 10) + h * 32 + w] = lds[w * 65 + t];
    }
}

// ---------------------------------------------------------------------------
// conv3x3_allco: one thread = one pixel x 8 output channels (encoder convs).
// ---------------------------------------------------------------------------
template<int CIN1, int CIN2, int COUT, int H, int W, bool UP1, bool RELU>
__global__ __launch_bounds__(256)
void conv3x3_allco_kernel(const float* __restrict__ in1, const float* __restrict__ in2,
                          const float* __restrict__ wgt, const float* __restrict__ bias,
                          float* __restrict__ out) {
    constexpr int CTOT = CIN1 + CIN2;
    constexpr int NW = CTOT * 9 * COUT;      // [r=(ci,kh,kw)][co]
    constexpr int NCOG = COUT / 8;
    static_assert(COUT % 8 == 0, "COUT % 8");
    __shared__ __align__(16) float wl[NW];
    for (int i = threadIdx.x; i < NW; i += 256) {
        int co = i % COUT, r = i / COUT;
        wl[i] = wgt[co * CTOT * 9 + r];      // transpose OIHW -> [r][co]
    }
    __syncthreads();

    int tid = blockIdx.x * 256 + threadIdx.x;
    int x0  = tid % W;
    int y0  = (tid / W) % H;
    int cog = (tid / (W * H)) % NCOG;
    int f   = tid / (W * H * NCOG);

    float acc[8];
#pragma unroll
    for (int c = 0; c < 8; ++c) acc[c] = bias[cog * 8 + c];

    const float4* wl4 = reinterpret_cast<const float4*>(wl);
    const int wsel = cog * 2;

    for (int ci = 0; ci < CIN1; ++ci) {
        const float* ib;
        if (UP1) ib = in1 + (size_t)(f * CIN1 + ci) * (H / 2) * (W / 2);
        else     ib = in1 + (size_t)(f * CIN1 + ci) * H * W;
#pragma unroll
        for (int kh = 0; kh < 3; ++kh) {
            int yy = y0 + kh - 1;
            if (yy < 0 || yy >= H) continue;
#pragma unroll
            for (int kw = 0; kw < 3; ++kw) {
                int xx = x0 + kw - 1;
                if (xx < 0 || xx >= W) continue;
                float v;
                if (UP1) v = ib[(yy >> 1) * (W / 2) + (xx >> 1)];
                else     v = ib[yy * W + xx];
                int r = ci * 9 + kh * 3 + kw;
                float4 w0 = wl4[r * (COUT / 4) + wsel];
                float4 w1 = wl4[r * (COUT / 4) + wsel + 1];
                acc[0] = fmaf(v, w0.x, acc[0]); acc[1] = fmaf(v, w0.y, acc[1]);
                acc[2] = fmaf(v, w0.z, acc[2]); acc[3] = fmaf(v, w0.w, acc[3]);
                acc[4] = fmaf(v, w1.x, acc[4]); acc[5] = fmaf(v, w1.y, acc[5]);
                acc[6] = fmaf(v, w1.z, acc[6]); acc[7] = fmaf(v, w1.w, acc[7]);
            }
        }
    }
    if constexpr (CIN2 > 0) {
        for (int ci2 = 0; ci2 < CIN2; ++ci2) {
            const float* ib = in2 + (size_t)(f * CIN2 + ci2) * H * W;
#pragma unroll
            for (int kh = 0; kh < 3; ++kh) {
                int yy = y0 + kh - 1;
                if (yy < 0 || yy >= H) continue;
#pragma unroll
                for (int kw = 0; kw < 3; ++kw) {
                    int xx = x0 + kw - 1;
                    if (xx < 0 || xx >= W) continue;
                    float v = ib[yy * W + xx];
                    int r = (CIN1 + ci2) * 9 + kh * 3 + kw;
                    float4 w0 = wl4[r * (COUT / 4) + wsel];
                    float4 w1 = wl4[r * (COUT / 4) + wsel + 1];
                    acc[0] = fmaf(v, w0.x, acc[0]); acc[1] = fmaf(v, w0.y, acc[1]);
                    acc[2] = fmaf(v, w0.z, acc[2]); acc[3] = fmaf(v, w0.w, acc[3]);
                    acc[4] = fmaf(v, w1.x, acc[4]); acc[5] = fmaf(v, w1.y, acc[5]);
                    acc[6] = fmaf(v, w1.z, acc[6]); acc[7] = fmaf(v, w1.w, acc[7]);
                }
            }
        }
    }

    size_t ob = (size_t)(f * COUT + cog * 8) * (H * W) + y0 * W + x0;
#pragma unroll
    for (int c = 0; c < 8; ++c) {
        float vv = acc[c];
        if (RELU) vv = fmaxf(vv, 0.0f);
        out[ob + (size_t)c * (H * W)] = vv;
    }
}

// ---------------------------------------------------------------------------
// conv3x3_up_q22: decoder conv. One thread = 2x2 output quad x 8 co.
// in1 is 2x-upsampled (src H/2 x W/2): the even-aligned 2x2 quad reads only a
// 3x3 source region (4x fewer loads); tap->source index is compile-time:
//   syi[dy][kh] = {{0,1,1},{1,1,2}} (same for x). Zeroed halo gives exact
//   SAME-padding semantics in the upsampled domain.
// in2 (skip, full res) reads a 4x4 region, row = dy+kh, col = dx+kw.
// Branchless: clamped addresses, unconditional loads, select-to-zero.
// ---------------------------------------------------------------------------
template<int CIN1, int CIN2, int COUT, int H, int W, bool RELU>
__global__ __launch_bounds__(256)
void conv3x3_up_q22_kernel(const float* __restrict__ in1, const float* __restrict__ in2,
                           const float* __restrict__ wgt, const float* __restrict__ bias,
                           float* __restrict__ out) {
    constexpr int CTOT = CIN1 + CIN2;
    constexpr int NW = CTOT * 9 * COUT;
    constexpr int NCOG = COUT / 8;
    constexpr int H2 = H / 2, W2 = W / 2;
    static_assert(COUT % 8 == 0, "COUT % 8");
    __shared__ __align__(16) float wl[NW];
    for (int i = threadIdx.x; i < NW; i += 256) {
        int co = i % COUT, r = i / COUT;
        wl[i] = wgt[co * CTOT * 9 + r];      // transpose OIHW -> [r][co]
    }
    __syncthreads();

    int tid = blockIdx.x * 256 + threadIdx.x;
    int xq  = tid % W2;
    int yq  = (tid / W2) % H2;
    int cog = (tid / (W2 * H2)) % NCOG;
    int f   = tid / (W2 * H2 * NCOG);

    float acc[4][8];
#pragma unroll
    for (int p = 0; p < 4; ++p)
#pragma unroll
        for (int c = 0; c < 8; ++c) acc[p][c] = bias[cog * 8 + c];

    const float4* wl4 = reinterpret_cast<const float4*>(wl);
    const int wsel = cog * 2;

    const bool by0 = (yq > 0), by2 = (yq < H2 - 1);
    const bool bx0 = (xq > 0), bx2 = (xq < W2 - 1);
    const int ym = by0 ? yq - 1 : 0, yp = by2 ? yq + 1 : H2 - 1;
    const int xm = bx0 ? xq - 1 : 0, xp = bx2 ? xq + 1 : W2 - 1;

    // ---- in1: upsampled channels, 3x3 source region per quad ----
    for (int ci = 0; ci < CIN1; ++ci) {
        const float* ib = in1 + (size_t)(f * CIN1 + ci) * (H2 * W2);
        float s[3][3];
        s[0][0] = ib[ym * W2 + xm]; s[0][1] = ib[ym * W2 + xq]; s[0][2] = ib[ym * W2 + xp];
        s[1][0] = ib[yq * W2 + xm]; s[1][1] = ib[yq * W2 + xq]; s[1][2] = ib[yq * W2 + xp];
        s[2][0] = ib[yp * W2 + xm]; s[2][1] = ib[yp * W2 + xq]; s[2][2] = ib[yp * W2 + xp];
        s[0][0] = (by0 && bx0) ? s[0][0] : 0.f;
        s[0][1] = by0 ? s[0][1] : 0.f;
        s[0][2] = (by0 && bx2) ? s[0][2] : 0.f;
        s[1][0] = bx0 ? s[1][0] : 0.f;
        s[1][2] = bx2 ? s[1][2] : 0.f;
        s[2][0] = (by2 && bx0) ? s[2][0] : 0.f;
        s[2][1] = by2 ? s[2][1] : 0.f;
        s[2][2] = (by2 && bx2) ? s[2][2] : 0.f;
#pragma unroll
        for (int kh = 0; kh < 3; ++kh) {
#pragma unroll
            for (int kw = 0; kw < 3; ++kw) {
                int r = ci * 9 + kh * 3 + kw;
                float4 w0 = wl4[r * (COUT / 4) + wsel];
                float4 w1 = wl4[r * (COUT / 4) + wsel + 1];
#pragma unroll
                for (int dy = 0; dy < 2; ++dy) {
                    const int sy = (dy == 0) ? ((kh == 0) ? 0 : 1) : ((kh == 2) ? 2 : 1);
#pragma unroll
                    for (int dx = 0; dx < 2; ++dx) {
                        const int sx = (dx == 0) ? ((kw == 0) ? 0 : 1) : ((kw == 2) ? 2 : 1);
                        const float v = s[sy][sx];
                        float* a = acc[dy * 2 + dx];
                        a[0] = fmaf(v, w0.x, a[0]); a[1] = fmaf(v, w0.y, a[1]);
                        a[2] = fmaf(v, w0.z, a[2]); a[3] = fmaf(v, w0.w, a[3]);
                        a[4] = fmaf(v, w1.x, a[4]); a[5] = fmaf(v, w1.y, a[5]);
                        a[6] = fmaf(v, w1.z, a[6]); a[7] = fmaf(v, w1.w, a[7]);
                    }
                }
            }
        }
    }

    // ---- in2: skip channels, 4x4 region per quad ----
    if constexpr (CIN2 > 0) {
        const int y2 = 2 * yq, x2 = 2 * xq;
        const int R0 = by0 ? y2 - 1 : 0, R3 = by2 ? y2 + 2 : H - 1;
        const int C0 = bx0 ? x2 - 1 : 0, C3 = bx2 ? x2 + 2 : W - 1;
        const int rr[4] = {R0, y2, y2 + 1, R3};
        const int cc[4] = {C0, x2, x2 + 1, C3};
        for (int ci2 = 0; ci2 < CIN2; ++ci2) {
            const float* ib = in2 + (size_t)(f * CIN2 + ci2) * (H * W);
            float t[4][4];
#pragma unroll
            for (int i = 0; i < 4; ++i)
#pragma unroll
                for (int j = 0; j < 4; ++j) t[i][j] = ib[rr[i] * W + cc[j]];
            // zero invalid halo
#pragma unroll
            for (int j = 0; j < 4; ++j) { t[0][j] = by0 ? t[0][j] : 0.f; t[3][j] = by2 ? t[3][j] : 0.f; }
#pragma unroll
            for (int i = 0; i < 4; ++i) { t[i][0] = bx0 ? t[i][0] : 0.f; t[i][3] = bx2 ? t[i][3] : 0.f; }
#pragma unroll
            for (int kh = 0; kh < 3; ++kh) {
#pragma unroll
                for (int kw = 0; kw < 3; ++kw) {
                    int r = (CIN1 + ci2) * 9 + kh * 3 + kw;
                    float4 w0 = wl4[r * (COUT / 4) + wsel];
                    float4 w1 = wl4[r * (COUT / 4) + wsel + 1];
#pragma unroll
                    for (int dy = 0; dy < 2; ++dy) {
#pragma unroll
                        for (int dx = 0; dx < 2; ++dx) {
                            const float v = t[dy + kh][dx + kw];
                            float* a = acc[dy * 2 + dx];
                            a[0] = fmaf(v, w0.x, a[0]); a[1] = fmaf(v, w0.y, a[1]);
                            a[2] = fmaf(v, w0.z, a[2]); a[3] = fmaf(v, w0.w, a[3]);
                            a[4] = fmaf(v, w1.x, a[4]); a[5] = fmaf(v, w1.y, a[5]);
                            a[6] = fmaf(v, w1.z, a[6]); a[7] = fmaf(v, w1.w, a[7]);
                        }
                    }
                }
            }
        }
    }

    const size_t ob = (size_t)(f * COUT + cog * 8) * (H * W);
#pragma unroll
    for (int dy = 0; dy < 2; ++dy)
#pragma unroll
        for (int dx = 0; dx < 2; ++dx) {
            const int p = dy * 2 + dx;
            const size_t pb = ob + (size_t)(2 * yq + dy) * W + (2 * xq + dx);
#pragma unroll
            for (int c = 0; c < 8; ++c) {
                float vv = acc[p][c];
                if (RELU) vv = fmaxf(vv, 0.0f);
                out[pb + (size_t)c * (H * W)] = vv;
            }
        }
}

// ---------------------------------------------------------------------------
// 2x2 max pool, stride 2
// ---------------------------------------------------------------------------
template<int CH, int H, int W>
__global__ __launch_bounds__(256)
void pool2_kernel(const float* __restrict__ in, float* __restrict__ out) {
    int tid = blockIdx.x * 256 + threadIdx.x;
    constexpr int total = F * CH * (H / 2) * (W / 2);
    if (tid >= total) return;
    int x = tid % (W / 2);
    int y = (tid / (W / 2)) % (H / 2);
    int fc = tid / ((W / 2) * (H / 2));   // f*CH + c
    const float* ib = in + (size_t)fc * H * W + (2 * y) * W + 2 * x;
    float m = fmaxf(fmaxf(ib[0], ib[1]), fmaxf(ib[W], ib[W + 1]));
    out[tid] = m;
}

// ---------------------------------------------------------------------------
// 1x1 out-conv (8->2) + softmax over [l0, l1, 1] + mask*x -> feat bf16 [F,6144]
// ---------------------------------------------------------------------------
__global__ __launch_bounds__(256)
void maskfeat_kernel(const float* __restrict__ d1, const float* __restrict__ xt,
                     const float* __restrict__ ow, const float* __restrict__ ob,
                     ushort* __restrict__ feat) {
    int tid = blockIdx.x * 256 + threadIdx.x;
    if (tid >= F * 1024) return;
    int hw = tid & 1023;
    int f  = tid >> 10;
    const float* db = d1 + ((size_t)f << 13) + hw;   // f*8*1024
    float l0 = ob[0], l1 = ob[1];
#pragma unroll
    for (int c = 0; c < 8; ++c) {
        float v = db[c << 10];
        l0 = fmaf(v, ow[c], l0);
        l1 = fmaf(v, ow[8 + c], l1);
    }
    float mx = fmaxf(fmaxf(l0, l1), 1.0f);
    float e0 = expf(l0 - mx), e1 = expf(l1 - mx), e2 = expf(1.0f - mx);
    float inv = 1.0f / (e0 + e1 + e2);
    float m0 = e0 * inv, m1 = e1 * inv;
    const float* xb = xt + (size_t)f * 3072 + hw;
    ushort* fb = feat + (size_t)f * 6144 + hw;
#pragma unroll
    for (int c = 0; c < 3; ++c) {
        float xv = xb[c << 10];
        fb[c << 10]          = f2bf(m0 * xv);
        fb[3072 + (c << 10)] = f2bf(m1 * xv);
    }
}

// ---------------------------------------------------------------------------
// W1 prep: W1[6144][200] fp32 -> BT[224][6144] bf16 (pad n>=200 with 0).
// ---------------------------------------------------------------------------
__global__ __launch_bounds__(256)
void w1prep_kernel(const float* __restrict__ W, ushort* __restrict__ BT) {
    __shared__ float t[32][33];
    int kb = blockIdx.x % 192, nb = blockIdx.x / 192;
    int k0 = kb * 32, n0 = nb * 32;
    int r = threadIdx.x / 32, c = threadIdx.x % 32;
#pragma unroll
    for (int p = 0; p < 4; ++p) {
        int kk = r + p * 8;
        int n = n0 + c;
        t[kk][c] = (n < 200) ? W[(size_t)(k0 + kk) * 200 + n] : 0.0f;
    }
    __syncthreads();
#pragma unroll
    for (int p = 0; p < 4; ++p) {
        int nn = r + p * 8;
        BT[(size_t)(n0 + nn) * 6144 + k0 + c] = f2bf(t[c][nn]);
    }
}

// ---------------------------------------------------------------------------
// FC1 MFMA: P[kc][2048][224] partial = A[2048][6144]bf16 x BT^T, K-chunk 384.
// ---------------------------------------------------------------------------
__global__ __launch_bounds__(128)
void fc1_mfma_kernel(const ushort* __restrict__ A, const ushort* __restrict__ BT,
                     float* __restrict__ P) {
    int bid = blockIdx.x;
    int mb = bid & 15;
    int nb = (bid >> 4) % 7;
    int kc = bid / (16 * 7);
    int w = threadIdx.x >> 6, lane = threadIdx.x & 63;
    int m0 = mb * 128 + w * 64;
    int n0 = nb * 32;
    int row16 = lane & 15, kgrp = lane >> 4;

    f32x4 acc00 = {0,0,0,0}, acc01 = {0,0,0,0}, acc10 = {0,0,0,0}, acc11 = {0,0,0,0};
    f32x4 acc20 = {0,0,0,0}, acc21 = {0,0,0,0}, acc30 = {0,0,0,0}, acc31 = {0,0,0,0};

    const ushort* aB = A  + (size_t)(m0 + row16) * 6144 + kgrp * 8;
    const ushort* bB = BT + (size_t)(n0 + row16) * 6144 + kgrp * 8;
    int kend = kc * 384 + 384;
    for (int k = kc * 384; k < kend; k += 32) {
        bf16x8 b0 = *(const bf16x8*)(bB + k);
        bf16x8 b1 = *(const bf16x8*)(bB + 16 * 6144 + k);
        bf16x8 a0 = *(const bf16x8*)(aB + k);
        bf16x8 a1 = *(const bf16x8*)(aB + 16 * 6144 + k);
        bf16x8 a2 = *(const bf16x8*)(aB + 32 * 6144 + k);
        bf16x8 a3 = *(const bf16x8*)(aB + 48 * 6144 + k);
        acc00 = __builtin_amdgcn_mfma_f32_16x16x32_bf16(a0, b0, acc00, 0, 0, 0);
        acc01 = __builtin_amdgcn_mfma_f32_16x16x32_bf16(a0, b1, acc01, 0, 0, 0);
        acc10 = __builtin_amdgcn_mfma_f32_16x16x32_bf16(a1, b0, acc10, 0, 0, 0);
        acc11 = __builtin_amdgcn_mfma_f32_16x16x32_bf16(a1, b1, acc11, 0, 0, 0);
        acc20 = __builtin_amdgcn_mfma_f32_16x16x32_bf16(a2, b0, acc20, 0, 0, 0);
        acc21 = __builtin_amdgcn_mfma_f32_16x16x32_bf16(a2, b1, acc21, 0, 0, 0);
        acc30 = __builtin_amdgcn_mfma_f32_16x16x32_bf16(a3, b0, acc30, 0, 0, 0);
        acc31 = __builtin_amdgcn_mfma_f32_16x16x32_bf16(a3, b1, acc31, 0, 0, 0);
    }

    float* Pb = P + (size_t)kc * 2048 * NP;
    const f32x4* accs[4][2] = {{&acc00,&acc01},{&acc10,&acc11},{&acc20,&acc21},{&acc30,&acc31}};
#pragma unroll
    for (int s = 0; s < 4; ++s) {
#pragma unroll
        for (int h = 0; h < 2; ++h) {
            const f32x4 v = *accs[s][h];
#pragma unroll
            for (int r = 0; r < 4; ++r) {
                int m = m0 + s * 16 + kgrp * 4 + r;
                int n = n0 + h * 16 + row16;
                Pb[(size_t)m * NP + n] = v[r];
            }
        }
    }
}

// ---------------------------------------------------------------------------
// FC1 reduce: H1[m][n] = relu(bias[n] + sum_kc P[kc][m][n]), n < 200
// ---------------------------------------------------------------------------
__global__ __launch_bounds__(256)
void fc1_reduce_kernel(const float* __restrict__ P, const float* __restrict__ bias,
                       float* __restrict__ H1) {
    int tid = blockIdx.x * 256 + threadIdx.x;
    if (tid >= F * 200) return;
    int n = tid % 200, m = tid / 200;
    float s = bias[n];
#pragma unroll
    for (int kc = 0; kc < KSPLIT; ++kc)
        s += P[((size_t)kc * 2048 + m) * NP + n];
    H1[(size_t)m * 200 + n] = fmaxf(s, 0.0f);
}

// ---------------------------------------------------------------------------
// Register-tiled FC (+ReLU): out[F,200] = relu(A[F,K] @ W[K,200] + b)
// ---------------------------------------------------------------------------
template<int K, int BK>
__global__ __launch_bounds__(256)
void fc_tiled_kernel(const float* __restrict__ A, const float* __restrict__ Wm,
                     const float* __restrict__ bias, float* __restrict__ out) {
    constexpr int BM = 8, N = 200;
    static_assert(K % BK == 0, "K % BK");
    __shared__ float As[BM * BK];
    int t = threadIdx.x;
    int row0 = blockIdx.x * BM;
    int tx = t % 25, ty = t / 25;
    bool active = (ty < BM);
    int c0 = tx * 8;
    float acc0 = 0.f, acc1 = 0.f, acc2 = 0.f, acc3 = 0.f;
    float acc4 = 0.f, acc5 = 0.f, acc6 = 0.f, acc7 = 0.f;

    for (int kb = 0; kb < K; kb += BK) {
        for (int i = t; i < BM * BK; i += 256) {
            int r = i / BK, kk = i % BK;
            As[i] = A[(size_t)(row0 + r) * K + kb + kk];
        }
        __syncthreads();
        if (active) {
#pragma unroll
            for (int kk = 0; kk < BK; ++kk) {
                float a = As[ty * BK + kk];
                const float4* wp =
                    reinterpret_cast<const float4*>(Wm + (size_t)(kb + kk) * N + c0);
                float4 w0 = wp[0], w1 = wp[1];
                acc0 = fmaf(a, w0.x, acc0); acc1 = fmaf(a, w0.y, acc1);
                acc2 = fmaf(a, w0.z, acc2); acc3 = fmaf(a, w0.w, acc3);
                acc4 = fmaf(a, w1.x, acc4); acc5 = fmaf(a, w1.y, acc5);
                acc6 = fmaf(a, w1.z, acc6); acc7 = fmaf(a, w1.w, acc7);
            }
        }
        __syncthreads();
    }
    if (active) {
        const float4* bp = reinterpret_cast<const float4*>(bias + c0);
        float4 b0 = bp[0], b1 = bp[1];
        float4 o0, o1;
        o0.x = fmaxf(acc0 + b0.x, 0.f); o0.y = fmaxf(acc1 + b0.y, 0.f);
        o0.z = fmaxf(acc2 + b0.z, 0.f); o0.w = fmaxf(acc3 + b0.w, 0.f);
        o1.x = fmaxf(acc4 + b1.x, 0.f); o1.y = fmaxf(acc5 + b1.y, 0.f);
        o1.z = fmaxf(acc6 + b1.z, 0.f); o1.w = fmaxf(acc7 + b1.w, 0.f);
        float4* op = reinterpret_cast<float4*>(out + (size_t)(row0 + ty) * N + c0);
        op[0] = o0; op[1] = o1;
    }
}

// ---------------------------------------------------------------------------
// FC3 (200 -> 4) + tanh epilogue: one thread per frame, W3 staged in LDS.
// ---------------------------------------------------------------------------
__global__ __launch_bounds__(256)
void fc3_tanh_kernel(const float* __restrict__ A, const float* __restrict__ Wm,
                     const float* __restrict__ bias, float* __restrict__ out) {
    __shared__ float wl[800];
    int t = threadIdx.x;
#pragma unroll
    for (int j = 0; j < 4; ++j) {
        int i = t + j * 256;
        if (i < 800) wl[i] = Wm[i];
    }
    __syncthreads();
    int row = blockIdx.x * 256 + t;
    float a0 = bias[0], a1 = bias[1], a2 = bias[2], a3 = bias[3];
    const float* ar = A + (size_t)row * 200;
#pragma unroll 8
    for (int k = 0; k < 200; ++k) {
        float a = ar[k];
        const float4 w = *reinterpret_cast<const float4*>(&wl[k * 4]);
        a0 = fmaf(a, w.x, a0); a1 = fmaf(a, w.y, a1);
        a2 = fmaf(a, w.z, a2); a3 = fmaf(a, w.w, a3);
    }
    float4 o;
    o.x = tanhf(a0) * 16.0f + 16.0f;
    o.y = tanhf(a1) * 16.0f + 16.0f;
    o.z = tanhf(a2) * 16.0f + 16.0f;
    o.w = tanhf(a3) * 16.0f + 16.0f;
    *reinterpret_cast<float4*>(out + (size_t)row * 4) = o;
}

// ---------------------------------------------------------------------------
extern "C" void kernel_launch(void* const* d_in, const int* in_sizes, int n_in,
                              void* d_out, int out_size, void* d_ws, size_t ws_size,
                              hipStream_t stream) {
    const float* x      = (const float*)d_in[0];
    const float* enc_w1 = (const float*)d_in[1];
    const float* enc_b1 = (const float*)d_in[2];
    const float* enc_w2 = (const float*)d_in[3];
    const float* enc_b2 = (const float*)d_in[4];
    const float* enc_w3 = (const float*)d_in[5];
    const float* enc_b3 = (const float*)d_in[6];
    const float* dec_w2 = (const float*)d_in[7];
    const float* dec_b2 = (const float*)d_in[8];
    const float* dec_w1 = (const float*)d_in[9];
    const float* dec_b1 = (const float*)d_in[10];
    const float* out_w  = (const float*)d_in[11];
    const float* out_b  = (const float*)d_in[12];
    const float* loc_w1 = (const float*)d_in[13];
    const float* loc_b1 = (const float*)d_in[14];
    const float* loc_w2 = (const float*)d_in[15];
    const float* loc_b2 = (const float*)d_in[16];
    const float* loc_w3 = (const float*)d_in[17];
    const float* loc_b3 = (const float*)d_in[18];
    float* out = (float*)d_out;

    // ---- Workspace layout (floats), peak 39,845,888 floats = 152 MB ----
    // S region liveness: P/E2/E3 (encoder+dec2) -> D1 -> {H1,H2,P16,BT}
    // E1 region: E1 (until dec1) -> FEATB (bf16)
    float* ws = (float*)d_ws;
    float* XT = ws;                          //  6,291,456  [2048,3,32,32]
    float* E1 = XT + 6291456;                // 16,777,216  [2048,8,32,32]
    float* S  = E1 + 16777216;               // 16,777,216  shared region
    float* P  = S;                           //  4,194,304  pool scratch
    float* E2 = S + 4194304;                 //  8,388,608  [2048,16,16,16]
    float* E3 = S + 4194304 + 8388608;       //  4,194,304  [2048,32,8,8]
    float* D2 = S + 16777216;                //  8,388,608  [2048,16,16,16]
    float* D1 = S;                           // 16,777,216  (P/E2/E3 dead)
    ushort* FEATB = (ushort*)E1;             // 12,582,912 bf16 (E1 dead)
    float* H1 = S;                           //    409,600  (D1 dead)
    float* H2 = S + 409600;                  //    409,600
    float* P16 = S + 819200;                 //  7,340,032  [16,2048,224] fp32
    ushort* BT = (ushort*)(S + 8159232);     //  1,376,256 bf16 [224,6144]
    (void)ws_size; (void)in_sizes; (void)n_in; (void)out_size;

    transpose_kernel<<<Bc * Cc * Hc, 256, 0, stream>>>(x, XT);

    // encoder
    conv3x3_allco_kernel<3, 0, 8, 32, 32, false, true><<<8192, 256, 0, stream>>>(
        XT, nullptr, enc_w1, enc_b1, E1);
    pool2_kernel<8, 32, 32><<<4194304 / 256, 256, 0, stream>>>(E1, P);
    conv3x3_allco_kernel<8, 0, 16, 16, 16, false, true><<<4096, 256, 0, stream>>>(
        P, nullptr, enc_w2, enc_b2, E2);
    pool2_kernel<16, 16, 16><<<2097152 / 256, 256, 0, stream>>>(E2, P);
    conv3x3_allco_kernel<16, 0, 32, 8, 8, false, true><<<2048, 256, 0, stream>>>(
        P, nullptr, enc_w3, enc_b3, E3);

    // decoder: 2x2-quad threads (upsample reuse), implicit concat [up(deep), skip]
    conv3x3_up_q22_kernel<32, 16, 16, 16, 16, true><<<1024, 256, 0, stream>>>(
        E3, E2, dec_w2, dec_b2, D2);
    conv3x3_up_q22_kernel<16, 8, 8, 32, 32, true><<<2048, 256, 0, stream>>>(
        D2, E1, dec_w1, dec_b1, D1);

    // 1x1 conv + softmax(+ones) + mask*x -> bf16 feat
    maskfeat_kernel<<<2097152 / 256, 256, 0, stream>>>(D1, XT, out_w, out_b, FEATB);

    // LocationNetwork: FC1 via bf16 MFMA split-K
    w1prep_kernel<<<192 * 7, 256, 0, stream>>>(loc_w1, BT);
    fc1_mfma_kernel<<<16 * 7 * KSPLIT, 128, 0, stream>>>(FEATB, BT, P16);
    fc1_reduce_kernel<<<(F * 200 + 255) / 256, 256, 0, stream>>>(P16, loc_b1, H1);
    fc_tiled_kernel<HID, 40><<<F / 8, 256, 0, stream>>>(H1, loc_w2, loc_b2, H2);
    fc3_tanh_kernel<<<F / 256, 256, 0, stream>>>(H2, loc_w3, loc_b3, out);
}

// Round 12
// 546.554 us; speedup vs baseline: 10.5293x; 1.1306x over previous
//
#include <hip/hip_runtime.h>

// Problem constants
constexpr int Bc = 32, Tc = 64, Cc = 3, Hc = 32, Wc = 32;
constexpr int F = Bc * Tc;              // 2048 frames
constexpr int FEATN = 2 * Cc * Hc * Wc; // 6144
constexpr int HID = 200;
constexpr int NP = 224;                 // padded N for FC1 (7 x 32)
constexpr int KSPLIT = 16;              // K chunks of 384

typedef __attribute__((ext_vector_type(8))) short bf16x8;
typedef __attribute__((ext_vector_type(4))) float f32x4;

static __device__ __forceinline__ ushort f2bf(float x) {
    union { float f; unsigned u; } v; v.f = x;
    unsigned r = (v.u + 0x7FFF + ((v.u >> 16) & 1)) >> 16;   // RNE
    return (ushort)r;
}

// ---------------------------------------------------------------------------
// Transpose [B,C,H,W,T] -> [B*T, C, H, W]   (frame f = b*T + t)
// ---------------------------------------------------------------------------
__global__ __launch_bounds__(256)
void transpose_kernel(const float* __restrict__ x, float* __restrict__ xt) {
    __shared__ float lds[32 * 65];
    int bid = blockIdx.x;                 // ((b*3 + c)*32 + h)
    int h = bid & 31;
    int c = (bid >> 5) % 3;
    int b = bid / (3 * 32);
    const float* src = x + (size_t)bid * 2048;   // [w][t] tile, contiguous
#pragma unroll
    for (int j = 0; j < 8; ++j) {
        int i = threadIdx.x + j * 256;           // i = w*64 + t
        lds[(i >> 6) * 65 + (i & 63)] = src[i];
    }
    __syncthreads();
#pragma unroll
    for (int j = 0; j < 8; ++j) {
        int i = threadIdx.x + j * 256;           // i = t*32 + w
        int t = i >> 5, w = i & 31;
        int f = b * 64 + t;
        xt[((size_t)(f * 3 + c) << 10) + h * 32 + w] = lds[w * 65 + t];
    }
}

// ---------------------------------------------------------------------------
// conv3x3_q22: encoder conv. One thread = 2x2 output quad x 8 co.
// Full-res input, 4x4 region per quad (16 loads/ci for 4 px vs 36).
// Border taps become fmaf(0,w,acc) = exact no-op -> bit-identical to the
// guarded per-pixel version. Optional fused 2x2 maxpool (quad == pool window,
// max of post-ReLU values).
// Weights in LDS transposed [r=(ci,kh,kw)][co].
// Thread map: tid = ((f*NCOG + cog)*H2 + yq)*W2 + xq.
// ---------------------------------------------------------------------------
template<int CIN, int COUT, int H, int W, bool POOL>
__global__ __launch_bounds__(256)
void conv3x3_q22_kernel(const float* __restrict__ in,
                        const float* __restrict__ wgt, const float* __restrict__ bias,
                        float* __restrict__ out, float* __restrict__ pout) {
    constexpr int NW = CIN * 9 * COUT;
    constexpr int NCOG = COUT / 8;
    constexpr int H2 = H / 2, W2 = W / 2;
    static_assert(COUT % 8 == 0, "COUT % 8");
    __shared__ __align__(16) float wl[NW];
    for (int i = threadIdx.x; i < NW; i += 256) {
        int co = i % COUT, r = i / COUT;
        wl[i] = wgt[co * CIN * 9 + r];       // transpose OIHW -> [r][co]
    }
    __syncthreads();

    int tid = blockIdx.x * 256 + threadIdx.x;
    int xq  = tid % W2;
    int yq  = (tid / W2) % H2;
    int cog = (tid / (W2 * H2)) % NCOG;
    int f   = tid / (W2 * H2 * NCOG);

    float acc[4][8];
#pragma unroll
    for (int p = 0; p < 4; ++p)
#pragma unroll
        for (int c = 0; c < 8; ++c) acc[p][c] = bias[cog * 8 + c];

    const float4* wl4 = reinterpret_cast<const float4*>(wl);
    const int wsel = cog * 2;

    const bool by0 = (yq > 0), by2 = (yq < H2 - 1);
    const bool bx0 = (xq > 0), bx2 = (xq < W2 - 1);
    const int y2 = 2 * yq, x2 = 2 * xq;
    const int R0 = by0 ? y2 - 1 : 0, R3 = by2 ? y2 + 2 : H - 1;
    const int C0 = bx0 ? x2 - 1 : 0, C3 = bx2 ? x2 + 2 : W - 1;
    const int rr[4] = {R0, y2, y2 + 1, R3};
    const int cc[4] = {C0, x2, x2 + 1, C3};

    for (int ci = 0; ci < CIN; ++ci) {
        const float* ib = in + (size_t)(f * CIN + ci) * (H * W);
        float t[4][4];
#pragma unroll
        for (int i = 0; i < 4; ++i)
#pragma unroll
            for (int j = 0; j < 4; ++j) t[i][j] = ib[rr[i] * W + cc[j]];
#pragma unroll
        for (int j = 0; j < 4; ++j) { t[0][j] = by0 ? t[0][j] : 0.f; t[3][j] = by2 ? t[3][j] : 0.f; }
#pragma unroll
        for (int i = 0; i < 4; ++i) { t[i][0] = bx0 ? t[i][0] : 0.f; t[i][3] = bx2 ? t[i][3] : 0.f; }
#pragma unroll
        for (int kh = 0; kh < 3; ++kh) {
#pragma unroll
            for (int kw = 0; kw < 3; ++kw) {
                int r = ci * 9 + kh * 3 + kw;
                float4 w0 = wl4[r * (COUT / 4) + wsel];
                float4 w1 = wl4[r * (COUT / 4) + wsel + 1];
#pragma unroll
                for (int dy = 0; dy < 2; ++dy) {
#pragma unroll
                    for (int dx = 0; dx < 2; ++dx) {
                        const float v = t[dy + kh][dx + kw];
                        float* a = acc[dy * 2 + dx];
                        a[0] = fmaf(v, w0.x, a[0]); a[1] = fmaf(v, w0.y, a[1]);
                        a[2] = fmaf(v, w0.z, a[2]); a[3] = fmaf(v, w0.w, a[3]);
                        a[4] = fmaf(v, w1.x, a[4]); a[5] = fmaf(v, w1.y, a[5]);
                        a[6] = fmaf(v, w1.z, a[6]); a[7] = fmaf(v, w1.w, a[7]);
                    }
                }
            }
        }
    }

    const size_t ob = (size_t)(f * COUT + cog * 8) * (H * W);
#pragma unroll
    for (int c = 0; c < 8; ++c) {
        float v00 = fmaxf(acc[0][c], 0.0f), v01 = fmaxf(acc[1][c], 0.0f);
        float v10 = fmaxf(acc[2][c], 0.0f), v11 = fmaxf(acc[3][c], 0.0f);
        const size_t cb = ob + (size_t)c * (H * W);
        out[cb + (size_t)y2 * W + x2]           = v00;
        out[cb + (size_t)y2 * W + x2 + 1]       = v01;
        out[cb + (size_t)(y2 + 1) * W + x2]     = v10;
        out[cb + (size_t)(y2 + 1) * W + x2 + 1] = v11;
        if (POOL)
            pout[(size_t)(f * COUT + cog * 8 + c) * (H2 * W2) + yq * W2 + xq] =
                fmaxf(fmaxf(v00, v01), fmaxf(v10, v11));
    }
}

// ---------------------------------------------------------------------------
// conv3x3_up_q22: decoder conv. One thread = 2x2 output quad x 8 co.
// (unchanged from round 8 — verified: dec2 155 us, VALUBusy 55%)
// ---------------------------------------------------------------------------
template<int CIN1, int CIN2, int COUT, int H, int W, bool RELU>
__global__ __launch_bounds__(256)
void conv3x3_up_q22_kernel(const float* __restrict__ in1, const float* __restrict__ in2,
                           const float* __restrict__ wgt, const float* __restrict__ bias,
                           float* __restrict__ out) {
    constexpr int CTOT = CIN1 + CIN2;
    constexpr int NW = CTOT * 9 * COUT;
    constexpr int NCOG = COUT / 8;
    constexpr int H2 = H / 2, W2 = W / 2;
    static_assert(COUT % 8 == 0, "COUT % 8");
    __shared__ __align__(16) float wl[NW];
    for (int i = threadIdx.x; i < NW; i += 256) {
        int co = i % COUT, r = i / COUT;
        wl[i] = wgt[co * CTOT * 9 + r];      // transpose OIHW -> [r][co]
    }
    __syncthreads();

    int tid = blockIdx.x * 256 + threadIdx.x;
    int xq  = tid % W2;
    int yq  = (tid / W2) % H2;
    int cog = (tid / (W2 * H2)) % NCOG;
    int f   = tid / (W2 * H2 * NCOG);

    float acc[4][8];
#pragma unroll
    for (int p = 0; p < 4; ++p)
#pragma unroll
        for (int c = 0; c < 8; ++c) acc[p][c] = bias[cog * 8 + c];

    const float4* wl4 = reinterpret_cast<const float4*>(wl);
    const int wsel = cog * 2;

    const bool by0 = (yq > 0), by2 = (yq < H2 - 1);
    const bool bx0 = (xq > 0), bx2 = (xq < W2 - 1);
    const int ym = by0 ? yq - 1 : 0, yp = by2 ? yq + 1 : H2 - 1;
    const int xm = bx0 ? xq - 1 : 0, xp = bx2 ? xq + 1 : W2 - 1;

    // ---- in1: upsampled channels, 3x3 source region per quad ----
    for (int ci = 0; ci < CIN1; ++ci) {
        const float* ib = in1 + (size_t)(f * CIN1 + ci) * (H2 * W2);
        float s[3][3];
        s[0][0] = ib[ym * W2 + xm]; s[0][1] = ib[ym * W2 + xq]; s[0][2] = ib[ym * W2 + xp];
        s[1][0] = ib[yq * W2 + xm]; s[1][1] = ib[yq * W2 + xq]; s[1][2] = ib[yq * W2 + xp];
        s[2][0] = ib[yp * W2 + xm]; s[2][1] = ib[yp * W2 + xq]; s[2][2] = ib[yp * W2 + xp];
        s[0][0] = (by0 && bx0) ? s[0][0] : 0.f;
        s[0][1] = by0 ? s[0][1] : 0.f;
        s[0][2] = (by0 && bx2) ? s[0][2] : 0.f;
        s[1][0] = bx0 ? s[1][0] : 0.f;
        s[1][2] = bx2 ? s[1][2] : 0.f;
        s[2][0] = (by2 && bx0) ? s[2][0] : 0.f;
        s[2][1] = by2 ? s[2][1] : 0.f;
        s[2][2] = (by2 && bx2) ? s[2][2] : 0.f;
#pragma unroll
        for (int kh = 0; kh < 3; ++kh) {
#pragma unroll
            for (int kw = 0; kw < 3; ++kw) {
                int r = ci * 9 + kh * 3 + kw;
                float4 w0 = wl4[r * (COUT / 4) + wsel];
                float4 w1 = wl4[r * (COUT / 4) + wsel + 1];
#pragma unroll
                for (int dy = 0; dy < 2; ++dy) {
                    const int sy = (dy == 0) ? ((kh == 0) ? 0 : 1) : ((kh == 2) ? 2 : 1);
#pragma unroll
                    for (int dx = 0; dx < 2; ++dx) {
                        const int sx = (dx == 0) ? ((kw == 0) ? 0 : 1) : ((kw == 2) ? 2 : 1);
                        const float v = s[sy][sx];
                        float* a = acc[dy * 2 + dx];
                        a[0] = fmaf(v, w0.x, a[0]); a[1] = fmaf(v, w0.y, a[1]);
                        a[2] = fmaf(v, w0.z, a[2]); a[3] = fmaf(v, w0.w, a[3]);
                        a[4] = fmaf(v, w1.x, a[4]); a[5] = fmaf(v, w1.y, a[5]);
                        a[6] = fmaf(v, w1.z, a[6]); a[7] = fmaf(v, w1.w, a[7]);
                    }
                }
            }
        }
    }

    // ---- in2: skip channels, 4x4 region per quad ----
    if constexpr (CIN2 > 0) {
        const int y2 = 2 * yq, x2 = 2 * xq;
        const int R0 = by0 ? y2 - 1 : 0, R3 = by2 ? y2 + 2 : H - 1;
        const int C0 = bx0 ? x2 - 1 : 0, C3 = bx2 ? x2 + 2 : W - 1;
        const int rr[4] = {R0, y2, y2 + 1, R3};
        const int cc[4] = {C0, x2, x2 + 1, C3};
        for (int ci2 = 0; ci2 < CIN2; ++ci2) {
            const float* ib = in2 + (size_t)(f * CIN2 + ci2) * (H * W);
            float t[4][4];
#pragma unroll
            for (int i = 0; i < 4; ++i)
#pragma unroll
                for (int j = 0; j < 4; ++j) t[i][j] = ib[rr[i] * W + cc[j]];
#pragma unroll
            for (int j = 0; j < 4; ++j) { t[0][j] = by0 ? t[0][j] : 0.f; t[3][j] = by2 ? t[3][j] : 0.f; }
#pragma unroll
            for (int i = 0; i < 4; ++i) { t[i][0] = bx0 ? t[i][0] : 0.f; t[i][3] = bx2 ? t[i][3] : 0.f; }
#pragma unroll
            for (int kh = 0; kh < 3; ++kh) {
#pragma unroll
                for (int kw = 0; kw < 3; ++kw) {
                    int r = (CIN1 + ci2) * 9 + kh * 3 + kw;
                    float4 w0 = wl4[r * (COUT / 4) + wsel];
                    float4 w1 = wl4[r * (COUT / 4) + wsel + 1];
#pragma unroll
                    for (int dy = 0; dy < 2; ++dy) {
#pragma unroll
                        for (int dx = 0; dx < 2; ++dx) {
                            const float v = t[dy + kh][dx + kw];
                            float* a = acc[dy * 2 + dx];
                            a[0] = fmaf(v, w0.x, a[0]); a[1] = fmaf(v, w0.y, a[1]);
                            a[2] = fmaf(v, w0.z, a[2]); a[3] = fmaf(v, w0.w, a[3]);
                            a[4] = fmaf(v, w1.x, a[4]); a[5] = fmaf(v, w1.y, a[5]);
                            a[6] = fmaf(v, w1.z, a[6]); a[7] = fmaf(v, w1.w, a[7]);
                        }
                    }
                }
            }
        }
    }

    const size_t ob = (size_t)(f * COUT + cog * 8) * (H * W);
#pragma unroll
    for (int dy = 0; dy < 2; ++dy)
#pragma unroll
        for (int dx = 0; dx < 2; ++dx) {
            const int p = dy * 2 + dx;
            const size_t pb = ob + (size_t)(2 * yq + dy) * W + (2 * xq + dx);
#pragma unroll
            for (int c = 0; c < 8; ++c) {
                float vv = acc[p][c];
                if (RELU) vv = fmaxf(vv, 0.0f);
                out[pb + (size_t)c * (H * W)] = vv;
            }
        }
}

// ---------------------------------------------------------------------------
// 1x1 out-conv (8->2) + softmax over [l0, l1, 1] + mask*x -> feat bf16 [F,6144]
// ---------------------------------------------------------------------------
__global__ __launch_bounds__(256)
void maskfeat_kernel(const float* __restrict__ d1, const float* __restrict__ xt,
                     const float* __restrict__ ow, const float* __restrict__ ob,
                     ushort* __restrict__ feat) {
    int tid = blockIdx.x * 256 + threadIdx.x;
    if (tid >= F * 1024) return;
    int hw = tid & 1023;
    int f  = tid >> 10;
    const float* db = d1 + ((size_t)f << 13) + hw;   // f*8*1024
    float l0 = ob[0], l1 = ob[1];
#pragma unroll
    for (int c = 0; c < 8; ++c) {
        float v = db[c << 10];
        l0 = fmaf(v, ow[c], l0);
        l1 = fmaf(v, ow[8 + c], l1);
    }
    float mx = fmaxf(fmaxf(l0, l1), 1.0f);
    float e0 = expf(l0 - mx), e1 = expf(l1 - mx), e2 = expf(1.0f - mx);
    float inv = 1.0f / (e0 + e1 + e2);
    float m0 = e0 * inv, m1 = e1 * inv;
    const float* xb = xt + (size_t)f * 3072 + hw;
    ushort* fb = feat + (size_t)f * 6144 + hw;
#pragma unroll
    for (int c = 0; c < 3; ++c) {
        float xv = xb[c << 10];
        fb[c << 10]          = f2bf(m0 * xv);
        fb[3072 + (c << 10)] = f2bf(m1 * xv);
    }
}

// ---------------------------------------------------------------------------
// W1 prep: W1[6144][200] fp32 -> BT[224][6144] bf16 (pad n>=200 with 0).
// ---------------------------------------------------------------------------
__global__ __launch_bounds__(256)
void w1prep_kernel(const float* __restrict__ W, ushort* __restrict__ BT) {
    __shared__ float t[32][33];
    int kb = blockIdx.x % 192, nb = blockIdx.x / 192;
    int k0 = kb * 32, n0 = nb * 32;
    int r = threadIdx.x / 32, c = threadIdx.x % 32;
#pragma unroll
    for (int p = 0; p < 4; ++p) {
        int kk = r + p * 8;
        int n = n0 + c;
        t[kk][c] = (n < 200) ? W[(size_t)(k0 + kk) * 200 + n] : 0.0f;
    }
    __syncthreads();
#pragma unroll
    for (int p = 0; p < 4; ++p) {
        int nn = r + p * 8;
        BT[(size_t)(n0 + nn) * 6144 + k0 + c] = f2bf(t[c][nn]);
    }
}

// ---------------------------------------------------------------------------
// FC1 MFMA: P[kc][2048][224] partial = A[2048][6144]bf16 x BT^T, K-chunk 384.
// ---------------------------------------------------------------------------
__global__ __launch_bounds__(128)
void fc1_mfma_kernel(const ushort* __restrict__ A, const ushort* __restrict__ BT,
                     float* __restrict__ P) {
    int bid = blockIdx.x;
    int mb = bid & 15;
    int nb = (bid >> 4) % 7;
    int kc = bid / (16 * 7);
    int w = threadIdx.x >> 6, lane = threadIdx.x & 63;
    int m0 = mb * 128 + w * 64;
    int n0 = nb * 32;
    int row16 = lane & 15, kgrp = lane >> 4;

    f32x4 acc00 = {0,0,0,0}, acc01 = {0,0,0,0}, acc10 = {0,0,0,0}, acc11 = {0,0,0,0};
    f32x4 acc20 = {0,0,0,0}, acc21 = {0,0,0,0}, acc30 = {0,0,0,0}, acc31 = {0,0,0,0};

    const ushort* aB = A  + (size_t)(m0 + row16) * 6144 + kgrp * 8;
    const ushort* bB = BT + (size_t)(n0 + row16) * 6144 + kgrp * 8;
    int kend = kc * 384 + 384;
    for (int k = kc * 384; k < kend; k += 32) {
        bf16x8 b0 = *(const bf16x8*)(bB + k);
        bf16x8 b1 = *(const bf16x8*)(bB + 16 * 6144 + k);
        bf16x8 a0 = *(const bf16x8*)(aB + k);
        bf16x8 a1 = *(const bf16x8*)(aB + 16 * 6144 + k);
        bf16x8 a2 = *(const bf16x8*)(aB + 32 * 6144 + k);
        bf16x8 a3 = *(const bf16x8*)(aB + 48 * 6144 + k);
        acc00 = __builtin_amdgcn_mfma_f32_16x16x32_bf16(a0, b0, acc00, 0, 0, 0);
        acc01 = __builtin_amdgcn_mfma_f32_16x16x32_bf16(a0, b1, acc01, 0, 0, 0);
        acc10 = __builtin_amdgcn_mfma_f32_16x16x32_bf16(a1, b0, acc10, 0, 0, 0);
        acc11 = __builtin_amdgcn_mfma_f32_16x16x32_bf16(a1, b1, acc11, 0, 0, 0);
        acc20 = __builtin_amdgcn_mfma_f32_16x16x32_bf16(a2, b0, acc20, 0, 0, 0);
        acc21 = __builtin_amdgcn_mfma_f32_16x16x32_bf16(a2, b1, acc21, 0, 0, 0);
        acc30 = __builtin_amdgcn_mfma_f32_16x16x32_bf16(a3, b0, acc30, 0, 0, 0);
        acc31 = __builtin_amdgcn_mfma_f32_16x16x32_bf16(a3, b1, acc31, 0, 0, 0);
    }

    float* Pb = P + (size_t)kc * 2048 * NP;
    const f32x4* accs[4][2] = {{&acc00,&acc01},{&acc10,&acc11},{&acc20,&acc21},{&acc30,&acc31}};
#pragma unroll
    for (int s = 0; s < 4; ++s) {
#pragma unroll
        for (int h = 0; h < 2; ++h) {
            const f32x4 v = *accs[s][h];
#pragma unroll
            for (int r = 0; r < 4; ++r) {
                int m = m0 + s * 16 + kgrp * 4 + r;
                int n = n0 + h * 16 + row16;
                Pb[(size_t)m * NP + n] = v[r];
            }
        }
    }
}

// ---------------------------------------------------------------------------
// FC1 reduce: H1[m][n] = relu(bias[n] + sum_kc P[kc][m][n]), n < 200
// ---------------------------------------------------------------------------
__global__ __launch_bounds__(256)
void fc1_reduce_kernel(const float* __restrict__ P, const float* __restrict__ bias,
                       float* __restrict__ H1) {
    int tid = blockIdx.x * 256 + threadIdx.x;
    if (tid >= F * 200) return;
    int n = tid % 200, m = tid / 200;
    float s = bias[n];
#pragma unroll
    for (int kc = 0; kc < KSPLIT; ++kc)
        s += P[((size_t)kc * 2048 + m) * NP + n];
    H1[(size_t)m * 200 + n] = fmaxf(s, 0.0f);
}

// ---------------------------------------------------------------------------
// FC2 (+ReLU): one thread per (row,col); grid 1600 blocks (vs 256 for the old
// fc_tiled = 1 block/CU latency trap). W reads coalesced, A row L1-broadcast,
// 4 partial accumulators for ILP.
// ---------------------------------------------------------------------------
__global__ __launch_bounds__(256)
void fc2_kernel(const float* __restrict__ A, const float* __restrict__ Wm,
                const float* __restrict__ bias, float* __restrict__ out) {
    int tid = blockIdx.x * 256 + threadIdx.x;
    if (tid >= F * 200) return;
    int col = tid % 200, row = tid / 200;
    const float* ar = A + (size_t)row * 200;
    float s0 = 0.f, s1 = 0.f, s2 = 0.f, s3 = 0.f;
#pragma unroll 2
    for (int k = 0; k < 200; k += 4) {
        s0 = fmaf(ar[k],     Wm[(size_t)k * 200 + col],       s0);
        s1 = fmaf(ar[k + 1], Wm[(size_t)(k + 1) * 200 + col], s1);
        s2 = fmaf(ar[k + 2], Wm[(size_t)(k + 2) * 200 + col], s2);
        s3 = fmaf(ar[k + 3], Wm[(size_t)(k + 3) * 200 + col], s3);
    }
    out[tid] = fmaxf((s0 + s1) + (s2 + s3) + bias[col], 0.0f);
}

// ---------------------------------------------------------------------------
// FC3 (200 -> 4) + tanh epilogue: one thread per frame, W3 staged in LDS.
// ---------------------------------------------------------------------------
__global__ __launch_bounds__(256)
void fc3_tanh_kernel(const float* __restrict__ A, const float* __restrict__ Wm,
                     const float* __restrict__ bias, float* __restrict__ out) {
    __shared__ float wl[800];
    int t = threadIdx.x;
#pragma unroll
    for (int j = 0; j < 4; ++j) {
        int i = t + j * 256;
        if (i < 800) wl[i] = Wm[i];
    }
    __syncthreads();
    int row = blockIdx.x * 256 + t;
    float a0 = bias[0], a1 = bias[1], a2 = bias[2], a3 = bias[3];
    const float* ar = A + (size_t)row * 200;
#pragma unroll 8
    for (int k = 0; k < 200; ++k) {
        float a = ar[k];
        const float4 w = *reinterpret_cast<const float4*>(&wl[k * 4]);
        a0 = fmaf(a, w.x, a0); a1 = fmaf(a, w.y, a1);
        a2 = fmaf(a, w.z, a2); a3 = fmaf(a, w.w, a3);
    }
    float4 o;
    o.x = tanhf(a0) * 16.0f + 16.0f;
    o.y = tanhf(a1) * 16.0f + 16.0f;
    o.z = tanhf(a2) * 16.0f + 16.0f;
    o.w = tanhf(a3) * 16.0f + 16.0f;
    *reinterpret_cast<float4*>(out + (size_t)row * 4) = o;
}

// ---------------------------------------------------------------------------
extern "C" void kernel_launch(void* const* d_in, const int* in_sizes, int n_in,
                              void* d_out, int out_size, void* d_ws, size_t ws_size,
                              hipStream_t stream) {
    const float* x      = (const float*)d_in[0];
    const float* enc_w1 = (const float*)d_in[1];
    const float* enc_b1 = (const float*)d_in[2];
    const float* enc_w2 = (const float*)d_in[3];
    const float* enc_b2 = (const float*)d_in[4];
    const float* enc_w3 = (const float*)d_in[5];
    const float* enc_b3 = (const float*)d_in[6];
    const float* dec_w2 = (const float*)d_in[7];
    const float* dec_b2 = (const float*)d_in[8];
    const float* dec_w1 = (const float*)d_in[9];
    const float* dec_b1 = (const float*)d_in[10];
    const float* out_w  = (const float*)d_in[11];
    const float* out_b  = (const float*)d_in[12];
    const float* loc_w1 = (const float*)d_in[13];
    const float* loc_b1 = (const float*)d_in[14];
    const float* loc_w2 = (const float*)d_in[15];
    const float* loc_b2 = (const float*)d_in[16];
    const float* loc_w3 = (const float*)d_in[17];
    const float* loc_b3 = (const float*)d_in[18];
    float* out = (float*)d_out;

    // ---- Workspace layout (floats), peak 48,234,496 floats = 184 MB ----
    // S region liveness: P1/E2/E3 (encoder+dec2) -> D1 -> {H1,H2,P16,BT}
    // D2 region: P2 (enc2->enc3) -> D2 (dec2->dec1)
    // E1 region: E1 (until dec1) -> FEATB (bf16)
    float* ws = (float*)d_ws;
    float* XT = ws;                          //  6,291,456  [2048,3,32,32]
    float* E1 = XT + 6291456;                // 16,777,216  [2048,8,32,32]
    float* S  = E1 + 16777216;               // 16,777,216  shared region
    float* P1 = S;                           //  4,194,304  [2048,8,16,16]
    float* E2 = S + 4194304;                 //  8,388,608  [2048,16,16,16]
    float* E3 = S + 4194304 + 8388608;       //  4,194,304  [2048,32,8,8]
    float* D2 = S + 16777216;                //  8,388,608  [2048,16,16,16]
    float* P2 = D2;                          //  2,097,152  [2048,16,8,8] (dead before dec2 writes D2)
    float* D1 = S;                           // 16,777,216  (P1/E2/E3 dead)
    ushort* FEATB = (ushort*)E1;             // 12,582,912 bf16 (E1 dead)
    float* H1 = S;                           //    409,600  (D1 dead)
    float* H2 = S + 409600;                  //    409,600
    float* P16 = S + 819200;                 //  7,340,032  [16,2048,224] fp32
    ushort* BT = (ushort*)(S + 8159232);     //  1,376,256 bf16 [224,6144]
    (void)ws_size; (void)in_sizes; (void)n_in; (void)out_size;

    transpose_kernel<<<Bc * Cc * Hc, 256, 0, stream>>>(x, XT);

    // encoder: 2x2-quad convs with fused 2x2 maxpool
    conv3x3_q22_kernel<3, 8, 32, 32, true><<<2048, 256, 0, stream>>>(
        XT, enc_w1, enc_b1, E1, P1);
    conv3x3_q22_kernel<8, 16, 16, 16, true><<<1024, 256, 0, stream>>>(
        P1, enc_w2, enc_b2, E2, P2);
    conv3x3_q22_kernel<16, 32, 8, 8, false><<<512, 256, 0, stream>>>(
        P2, enc_w3, enc_b3, E3, nullptr);

    // decoder: 2x2-quad threads (upsample reuse), implicit concat [up(deep), skip]
    conv3x3_up_q22_kernel<32, 16, 16, 16, 16, true><<<1024, 256, 0, stream>>>(
        E3, E2, dec_w2, dec_b2, D2);
    conv3x3_up_q22_kernel<16, 8, 8, 32, 32, true><<<2048, 256, 0, stream>>>(
        D2, E1, dec_w1, dec_b1, D1);

    // 1x1 conv + softmax(+ones) + mask*x -> bf16 feat
    maskfeat_kernel<<<2097152 / 256, 256, 0, stream>>>(D1, XT, out_w, out_b, FEATB);

    // LocationNetwork: FC1 via bf16 MFMA split-K
    w1prep_kernel<<<192 * 7, 256, 0, stream>>>(loc_w1, BT);
    fc1_mfma_kernel<<<16 * 7 * KSPLIT, 128, 0, stream>>>(FEATB, BT, P16);
    fc1_reduce_kernel<<<(F * 200 + 255) / 256, 256, 0, stream>>>(P16, loc_b1, H1);
    fc2_kernel<<<(F * 200 + 255) / 256, 256, 0, stream>>>(H1, loc_w2, loc_b2, H2);
    fc3_tanh_kernel<<<F / 256, 256, 0, stream>>>(H2, loc_w3, loc_b3, out);
}